// Round 5
// baseline (323.583 us; speedup 1.0000x reference)
//
#include <hip/hip_runtime.h>

typedef __attribute__((ext_vector_type(8))) short short8;
typedef __attribute__((ext_vector_type(4))) float f32x4;
typedef unsigned long long u64;

__device__ __forceinline__ unsigned short f2bf(float f) {
  union { float f; unsigned u; } v; v.f = f;
  unsigned u = v.u;
  unsigned r = (u + 0x7FFFu + ((u >> 16) & 1u)) >> 16;  // RTNE
  return (unsigned short)r;
}
__device__ __forceinline__ float bf2f(unsigned short s) {
  union { unsigned u; float f; } v; v.u = ((unsigned)s) << 16;
  return v.f;
}

// async global->LDS, 16B per lane; LDS dest = wave-uniform base + lane*16
__device__ __forceinline__ void gl_lds16(const unsigned short* g, unsigned short* l) {
  __builtin_amdgcn_global_load_lds(
      (const __attribute__((address_space(1))) void*)g,
      (__attribute__((address_space(3))) void*)l, 16, 0, 0);
}

// ---------------- CSR build ----------------

__global__ void init_kernel(int* a, int n, int* b, int nb, int* flag,
                            const long long* edges, int nslots, int n_nodes) {
  int i = blockIdx.x * blockDim.x + threadIdx.x;
  int stride = gridDim.x * blockDim.x;
  for (int j = i; j < n; j += stride) a[j] = 0;
  for (int j = i; j < nb; j += stride) b[j] = 0;
  if (i == 0) *flag = 1;
  for (int j = i; j < nslots; j += stride) {
    long long v = edges[j];
    if (v < 0 || v >= n_nodes) atomicAnd(flag, 0);
  }
}

__device__ __forceinline__ int edge_at(const void* p, int is64, size_t idx) {
  return is64 ? (int)((const long long*)p)[idx] : ((const int*)p)[idx];
}

__global__ void count_kernel(const void* edges, int E, const int* flag, int* deg) {
  int is64 = *flag;
  int i = blockIdx.x * blockDim.x + threadIdx.x;
  int stride = gridDim.x * blockDim.x;
  for (int e = i; e < E; e += stride) {
    int d = edge_at(edges, is64, (size_t)E + e);
    atomicAdd(&deg[d], 1);
  }
}

__global__ void scan_kernel(const int* __restrict__ deg, int* __restrict__ rs,
                            float* __restrict__ invdeg, int n) {
  __shared__ int ssum[1024];
  int tid = threadIdx.x;
  int chunk = (n + 1023) >> 10;
  int start = tid * chunk;
  int end = min(start + chunk, n);
  int s = 0;
  for (int i = start; i < end; ++i) s += deg[i];
  ssum[tid] = s;
  __syncthreads();
  for (int off = 1; off < 1024; off <<= 1) {
    int t = (tid >= off) ? ssum[tid - off] : 0;
    __syncthreads();
    ssum[tid] += t;
    __syncthreads();
  }
  int run = (tid ? ssum[tid - 1] : 0);
  if (tid == 0) rs[0] = 0;
  for (int i = start; i < end; ++i) {
    int d = deg[i];
    run += d;
    rs[i + 1] = run;
    invdeg[i] = 1.0f / fmaxf((float)d, 1.0f);
  }
}

__global__ void fill_kernel(const void* edges, int E, const int* flag,
                            const int* __restrict__ rs, int* cursor, int* col_src) {
  int is64 = *flag;
  int i = blockIdx.x * blockDim.x + threadIdx.x;
  int stride = gridDim.x * blockDim.x;
  for (int e = i; e < E; e += stride) {
    int d = edge_at(edges, is64, (size_t)E + e);
    int s = edge_at(edges, is64, (size_t)e);
    int p = atomicAdd(&cursor[d], 1);
    col_src[rs[d] + p] = s;
  }
}

// ---------------- aggregation ----------------

__global__ void agg1_kernel(const float* __restrict__ x,
                            const int* __restrict__ rs, const int* __restrict__ cs,
                            const float* __restrict__ invdeg,
                            unsigned short* __restrict__ A1) {
  int node = blockIdx.x;
  int f = threadIdx.x;  // 128
  float xi = x[(size_t)node * 128 + f];
  float acc = 0.f;
  int e1 = rs[node + 1];
  for (int e = rs[node]; e < e1; ++e) {
    acc += x[(size_t)cs[e] * 128 + f];
  }
  A1[(size_t)node * 256 + f] = f2bf(acc * invdeg[node]);
  A1[(size_t)node * 256 + 128 + f] = f2bf(xi);
}

__global__ void agg2_kernel(const unsigned short* __restrict__ P2,
                            const int* __restrict__ rs, const int* __restrict__ cs,
                            const float* __restrict__ invdeg,
                            const float* __restrict__ b2,
                            unsigned short* __restrict__ h2) {
  int node = blockIdx.x;
  int f0 = threadIdx.x * 4;
  float acc0 = 0.f, acc1 = 0.f, acc2 = 0.f, acc3 = 0.f;
  int e1 = rs[node + 1];
  for (int e = rs[node]; e < e1; ++e) {
    int s = cs[e];
    u64 w = *reinterpret_cast<const u64*>(P2 + (size_t)s * 1024 + f0);
    acc0 += bf2f((unsigned short)w);
    acc1 += bf2f((unsigned short)(w >> 16));
    acc2 += bf2f((unsigned short)(w >> 32));
    acc3 += bf2f((unsigned short)(w >> 48));
  }
  float inv = invdeg[node];
  u64 wr = *reinterpret_cast<const u64*>(P2 + (size_t)node * 1024 + 512 + f0);
  float v0 = fmaxf(acc0 * inv + bf2f((unsigned short)wr) + b2[f0 + 0], 0.f);
  float v1 = fmaxf(acc1 * inv + bf2f((unsigned short)(wr >> 16)) + b2[f0 + 1], 0.f);
  float v2 = fmaxf(acc2 * inv + bf2f((unsigned short)(wr >> 32)) + b2[f0 + 2], 0.f);
  float v3 = fmaxf(acc3 * inv + bf2f((unsigned short)(wr >> 48)) + b2[f0 + 3], 0.f);
  u64 o = (u64)f2bf(v0) | ((u64)f2bf(v1) << 16) | ((u64)f2bf(v2) << 32) | ((u64)f2bf(v3) << 48);
  *reinterpret_cast<u64*>(h2 + (size_t)node * 512 + f0) = o;
}

__global__ void head_agg_kernel(const float* __restrict__ P3,
                                const int* __restrict__ rs, const int* __restrict__ cs,
                                const float* __restrict__ invdeg,
                                const float* __restrict__ bmu, const float* __restrict__ bls,
                                float* __restrict__ outmu, float* __restrict__ outls, int M) {
  int idx = blockIdx.x * blockDim.x + threadIdx.x;
  int node = idx >> 4;
  int c = idx & 15;
  if (node >= M) return;
  int relc = (c < 8) ? c : (16 + (c - 8));
  float acc = 0.f;
  int e1 = rs[node + 1];
  for (int e = rs[node]; e < e1; ++e) acc += P3[(size_t)cs[e] * 128 + relc];
  float v = acc * invdeg[node] + P3[(size_t)node * 128 + relc + 8]
          + ((c < 8) ? bmu[c] : bls[c - 8]);
  if (c < 8) outmu[(size_t)node * 8 + c] = v;
  else outls[(size_t)node * 8 + (c - 8)] = v;
}

// ---------------- weight transposes (LDS-tiled, coalesced) ----------------

__device__ __forceinline__ void ttile(const float* __restrict__ src, int Nw,
                                      unsigned short* __restrict__ dst, int ldd,
                                      int rowoff, int coloff,
                                      int tileIdx, int tilesN, float (*tile)[33]) {
  int tk = tileIdx / tilesN, tn = tileIdx % tilesN;
  int k0 = tk * 32, n0 = tn * 32;
  int tx = threadIdx.x & 31, ty = threadIdx.x >> 5;
#pragma unroll
  for (int s = 0; s < 4; ++s)
    tile[ty + s * 8][tx] = src[(size_t)(k0 + ty + s * 8) * Nw + n0 + tx];
  __syncthreads();
#pragma unroll
  for (int s = 0; s < 4; ++s)
    dst[(size_t)(rowoff + n0 + ty + s * 8) * ldd + coloff + k0 + tx] =
        f2bf(tile[tx][ty + s * 8]);
}

__global__ void wtrans_all_kernel(const float* __restrict__ w1_rel, const float* __restrict__ w1_root,
                                  const float* __restrict__ w2_rel, const float* __restrict__ w2_root,
                                  const float* __restrict__ wmu_rel, const float* __restrict__ wmu_root,
                                  const float* __restrict__ wls_rel, const float* __restrict__ wls_root,
                                  unsigned short* __restrict__ Bt1,
                                  unsigned short* __restrict__ Bt2,
                                  unsigned short* __restrict__ Bt3) {
  __shared__ float tile[32][33];
  int b = blockIdx.x;
  if (b < 128)       ttile(w1_rel, 1024, Bt1, 256, 0, 0, b, 32, tile);
  else if (b < 256)  ttile(w1_root, 1024, Bt1, 256, 0, 128, b - 128, 32, tile);
  else if (b < 768)  ttile(w2_rel, 512, Bt2, 1024, 0, 0, b - 256, 16, tile);
  else if (b < 1280) ttile(w2_root, 512, Bt2, 1024, 512, 0, b - 768, 16, tile);
  else {
    int idx = (b - 1280) * 256 + threadIdx.x;
    int n = idx >> 9, k = idx & 511;
    float v;
    if (n < 8) v = wmu_rel[(size_t)k * 8 + n];
    else if (n < 16) v = wmu_root[(size_t)k * 8 + (n - 8)];
    else if (n < 24) v = wls_rel[(size_t)k * 8 + (n - 16)];
    else v = wls_root[(size_t)k * 8 + (n - 24)];
    Bt3[(size_t)n * 512 + k] = f2bf(v);
  }
}

// ---------------- 8-phase 256x256 bf16 MFMA GEMM (T3+T4+T5) ----------------
// C[M][N] = A[M][K] * Bt[N][K]^T (+bias)(relu). BM=BN=256, BK=64, 8 waves.
// LDS: [dbuf 2][mat 2][khalf 2] regions of [256 rows][32 cols] bf16 = 128 KiB.
// Region layout makes every ds_read_b128 fragment a contiguous 1024B wave-read
// (conflict-free, no swizzle) and staging linear (global_load_lds-compatible).
// Caller guarantees: Mpad256 rows readable in A, N%256==0, K%128==0, K>=256.
#define R_(d, mat, kh) ((((d) * 2 + (mat)) * 2 + (kh)) * 8192)

__launch_bounds__(512, 2)
__global__ void gemm256_kernel(const unsigned short* __restrict__ A, int lda,
                               const unsigned short* __restrict__ Bt, int ldb,
                               const float* __restrict__ bias,
                               void* __restrict__ outp, int ldo,
                               int M, int N, int K, int relu, int out_f32, int gx) {
  __shared__ unsigned short sh[65536];  // 128 KiB
  const int tid = threadIdx.x;
  const int lane = tid & 63;
  const int w = tid >> 6;              // 0..7
  const int wr = w >> 2, wc = w & 3;   // 2M x 4N wave grid; per-wave out 128x64
  const int lr = lane & 15, lk = lane >> 4;
  const int lk8 = lk * 8;
  const int wrb = (wr * 128 + lr) * 32;
  const int wcb = (wc * 64 + lr) * 32;

  // bijective XCD swizzle (m204)
  int nwg = gridDim.x, orig = blockIdx.x;
  int q = nwg >> 3, r = nwg & 7;
  int xcd = orig & 7, lid = orig >> 3;
  int swz = (xcd < r ? xcd * (q + 1) : r * (q + 1) + (xcd - r) * q) + lid;
  int m0 = (swz / gx) * 256, n0 = (swz % gx) * 256;

  f32x4 acc[8][4];
#pragma unroll
  for (int i = 0; i < 8; ++i)
#pragma unroll
    for (int j = 0; j < 4; ++j) acc[i][j] = (f32x4)0.0f;

  // staging thread map: row r4 = tid>>2 (0..127 per issue), 16B slot s4 = tid&3
  const int r4 = tid >> 2, s4 = tid & 3;
  const unsigned short* pA = A + (size_t)(m0 + r4) * lda + s4 * 8;
  const unsigned short* pB = Bt + (size_t)(n0 + r4) * ldb + s4 * 8;

  // stage one 256x32 region (= K-half of a K-tile): 2 global_load_lds issues
  auto STG = [&](int d, int mat, int kh, int kt) {
    const unsigned short* g = (mat ? pB : pA) + (size_t)kt * 64 + kh * 32;
    size_t ld = mat ? (size_t)ldb : (size_t)lda;
    unsigned short* lb = sh + R_(d, mat, kh) + w * 512;
    gl_lds16(g, lb);                       // rows 0..127 of region
    gl_lds16(g + 128 * ld, lb + 4096);     // rows 128..255
  };

  // prologue: T0 -> dbuf0, T1 -> dbuf1 (16 gloads); wait T0 (8 in flight)
  STG(0, 0, 0, 0); STG(0, 0, 1, 0); STG(0, 1, 0, 0); STG(0, 1, 1, 0);
  STG(1, 0, 0, 1); STG(1, 0, 1, 1); STG(1, 1, 0, 1); STG(1, 1, 1, 1);
  asm volatile("s_waitcnt vmcnt(8)" ::: "memory");
  __builtin_amdgcn_s_barrier();

#define DSB(dd, kk)                                                            \
  _Pragma("unroll") for (int nf = 0; nf < 4; ++nf)                             \
      bfr[nf] = *reinterpret_cast<const short8*>(                              \
          &sh[R_(dd, 1, kk) + wcb + nf * 512 + lk8]);

#define PH(dd, kk, mh, DOB, STGSTMT, ENDW)                                     \
  {                                                                            \
    if (DOB) { DSB(dd, kk) }                                                   \
    short8 af[4];                                                              \
    _Pragma("unroll") for (int mf = 0; mf < 4; ++mf)                           \
        af[mf] = *reinterpret_cast<const short8*>(                             \
            &sh[R_(dd, 0, kk) + wrb + mh * 2048 + mf * 512 + lk8]);            \
    STGSTMT;                                                                   \
    __builtin_amdgcn_s_barrier();                                              \
    asm volatile("s_waitcnt lgkmcnt(0)" ::: "memory");                         \
    __builtin_amdgcn_s_setprio(1);                                             \
    _Pragma("unroll") for (int mf = 0; mf < 4; ++mf)                           \
        _Pragma("unroll") for (int nf = 0; nf < 4; ++nf)                       \
            acc[mh * 4 + mf][nf] = __builtin_amdgcn_mfma_f32_16x16x32_bf16(    \
                af[mf], bfr[nf], acc[mh * 4 + mf][nf], 0, 0, 0);               \
    __builtin_amdgcn_s_setprio(0);                                             \
    ENDW;                                                                      \
    __builtin_amdgcn_s_barrier();                                              \
  }

  const int niter = K >> 7;  // K/128
  short8 bfr[4];
  for (int i = 0; i < niter; ++i) {
    const bool first = (i == 0), last = (i == niter - 1);
    const int t1 = 2 * i + 1, t2 = 2 * i + 2, t3 = 2 * i + 3;

    PH(0, 0, 0, 1, if (!first) { STG(1, 0, 1, t1); }, )
    PH(0, 0, 1, 0, if (!first) { STG(1, 1, 1, t1); },
       if (last) { asm volatile("s_waitcnt vmcnt(4)" ::: "memory"); }
       else      { asm volatile("s_waitcnt vmcnt(6)" ::: "memory"); })
    PH(0, 1, 0, 1, if (!last) { STG(0, 0, 0, t2); }, )
    PH(0, 1, 1, 0, if (!last) { STG(0, 1, 0, t2); },
       if (last) { asm volatile("s_waitcnt vmcnt(2)" ::: "memory"); }
       else      { asm volatile("s_waitcnt vmcnt(6)" ::: "memory"); })
    PH(1, 0, 0, 1, if (!last) { STG(0, 0, 1, t2); }, )
    PH(1, 0, 1, 0, if (!last) { STG(0, 1, 1, t2); },
       if (last) { asm volatile("s_waitcnt vmcnt(0)" ::: "memory"); }
       else      { asm volatile("s_waitcnt vmcnt(6)" ::: "memory"); })
    PH(1, 1, 0, 1, if (!last) { STG(1, 0, 0, t3); }, )
    PH(1, 1, 1, 0, if (!last) { STG(1, 1, 0, t3); },
       if (!last) { asm volatile("s_waitcnt vmcnt(6)" ::: "memory"); })
  }
#undef PH
#undef DSB

  // epilogue: C-write. frag C layout: col = lane&15, row = (lane>>4)*4 + rr
#pragma unroll
  for (int mf8 = 0; mf8 < 8; ++mf8) {
    int row_b = m0 + wr * 128 + mf8 * 16 + lk * 4;
#pragma unroll
    for (int nf = 0; nf < 4; ++nf) {
      int col = n0 + wc * 64 + nf * 16 + lr;
      float bv = bias ? bias[col] : 0.f;
#pragma unroll
      for (int rr = 0; rr < 4; ++rr) {
        int row = row_b + rr;
        if (row < M) {
          float v = acc[mf8][nf][rr] + bv;
          if (relu) v = fmaxf(v, 0.f);
          if (out_f32) ((float*)outp)[(size_t)row * ldo + col] = v;
          else ((unsigned short*)outp)[(size_t)row * ldo + col] = f2bf(v);
        }
      }
    }
  }
}

// ---------------- 128x128 ring GEMM (heads; small N) ----------------
__launch_bounds__(256, 3)
__global__ void gemm128_kernel(const unsigned short* __restrict__ A, int lda,
                               const unsigned short* __restrict__ Bt, int ldb,
                               const float* __restrict__ bias,
                               void* __restrict__ outp, int ldo,
                               int M, int N, int K, int relu, int out_f32, int gx) {
  __shared__ unsigned short As[3 * 4096];
  __shared__ unsigned short Bs[3 * 4096];
  int tid = threadIdx.x;
  int lane = tid & 63;
  int w = tid >> 6;
  int wr = w >> 1, wc = w & 1;
  int lr = lane & 15, lk = lane >> 4;

  int nwg = gridDim.x, orig = blockIdx.x;
  int q = nwg >> 3, r = nwg & 7;
  int xcd = orig & 7, lid = orig >> 3;
  int swz = (xcd < r ? xcd * (q + 1) : r * (q + 1) + (xcd - r) * q) + lid;
  int m0 = (swz / gx) * 128, n0 = (swz % gx) * 128;

  f32x4 acc[4][4];
#pragma unroll
  for (int i = 0; i < 4; ++i)
#pragma unroll
    for (int j = 0; j < 4; ++j) acc[i][j] = (f32x4)0.0f;

  int r0 = tid >> 2;
  int slog = (tid & 3) ^ ((r0 >> 1) & 3);
  const unsigned short* gA = A + (size_t)(m0 + r0) * lda + slog * 8;
  const unsigned short* gB = Bt + (size_t)(n0 + r0) * ldb + slog * 8;
  size_t a64 = (size_t)64 * lda, b64 = (size_t)64 * ldb;
  unsigned short* wa = As + w * 512;
  unsigned short* wb = Bs + w * 512;
  int sw8 = (lk ^ ((lr >> 1) & 3)) * 8;

  int nt = K >> 5;
  gl_lds16(gA, wa); gl_lds16(gA + a64, wa + 2048);
  gl_lds16(gB, wb); gl_lds16(gB + b64, wb + 2048);
  gA += 32; gB += 32;
  gl_lds16(gA, wa + 4096); gl_lds16(gA + a64, wa + 6144);
  gl_lds16(gB, wb + 4096); gl_lds16(gB + b64, wb + 6144);
  gA += 32; gB += 32;
  asm volatile("s_waitcnt vmcnt(4)" ::: "memory");
  __builtin_amdgcn_s_barrier();

  int bufR = 0, bufS = 2;
  for (int t = 0; t < nt; ++t) {
    if (t + 2 < nt) {
      unsigned short* sa = As + bufS * 4096 + w * 512;
      unsigned short* sb = Bs + bufS * 4096 + w * 512;
      gl_lds16(gA, sa); gl_lds16(gA + a64, sa + 2048);
      gl_lds16(gB, sb); gl_lds16(gB + b64, sb + 2048);
      gA += 32; gB += 32;
    }
    const unsigned short* as_ = As + bufR * 4096;
    const unsigned short* bs_ = Bs + bufR * 4096;
    short8 af[4], bfr[4];
#pragma unroll
    for (int i = 0; i < 4; ++i) {
      af[i]  = *reinterpret_cast<const short8*>(&as_[(wr * 64 + i * 16 + lr) * 32 + sw8]);
      bfr[i] = *reinterpret_cast<const short8*>(&bs_[(wc * 64 + i * 16 + lr) * 32 + sw8]);
    }
    __builtin_amdgcn_s_setprio(1);
#pragma unroll
    for (int i = 0; i < 4; ++i)
#pragma unroll
      for (int j = 0; j < 4; ++j)
        acc[i][j] = __builtin_amdgcn_mfma_f32_16x16x32_bf16(af[i], bfr[j], acc[i][j], 0, 0, 0);
    __builtin_amdgcn_s_setprio(0);
    if (t + 1 < nt) {
      if (t + 2 < nt)
        asm volatile("s_waitcnt vmcnt(4) lgkmcnt(0)" ::: "memory");
      else
        asm volatile("s_waitcnt vmcnt(0) lgkmcnt(0)" ::: "memory");
      __builtin_amdgcn_s_barrier();
    }
    bufR = (bufR == 2) ? 0 : bufR + 1;
    bufS = (bufS == 2) ? 0 : bufS + 1;
  }

#pragma unroll
  for (int i = 0; i < 4; ++i) {
    int row_b = m0 + wr * 64 + i * 16 + lk * 4;
#pragma unroll
    for (int j = 0; j < 4; ++j) {
      int col = n0 + wc * 64 + j * 16 + lr;
      float bv = bias ? bias[col] : 0.f;
#pragma unroll
      for (int rr = 0; rr < 4; ++rr) {
        int row = row_b + rr;
        if (row < M) {
          float v = acc[i][j][rr] + bv;
          if (relu) v = fmaxf(v, 0.f);
          if (out_f32) ((float*)outp)[(size_t)row * ldo + col] = v;
          else ((unsigned short*)outp)[(size_t)row * ldo + col] = f2bf(v);
        }
      }
    }
  }
}

// ---------------- host ----------------

extern "C" void kernel_launch(void* const* d_in, const int* in_sizes, int n_in,
                              void* d_out, int out_size, void* d_ws, size_t ws_size,
                              hipStream_t stream) {
  const float* x = (const float*)d_in[0];
  const void* edge = d_in[1];
  const float* w1_rel = (const float*)d_in[2];
  const float* b1 = (const float*)d_in[3];
  const float* w1_root = (const float*)d_in[4];
  const float* w2_rel = (const float*)d_in[5];
  const float* b2 = (const float*)d_in[6];
  const float* w2_root = (const float*)d_in[7];
  const float* wmu_rel = (const float*)d_in[8];
  const float* bmu = (const float*)d_in[9];
  const float* wmu_root = (const float*)d_in[10];
  const float* wls_rel = (const float*)d_in[11];
  const float* bls = (const float*)d_in[12];
  const float* wls_root = (const float*)d_in[13];

  const int FIN = 128, H1 = 1024, H2 = 512;
  const int M = in_sizes[0] / FIN;   // 20000
  const int E = in_sizes[1] / 2;     // 160000
  const int Mpad = ((M + 255) / 256) * 256;   // 20224 (also covers 128-align)
  const int gy256 = Mpad / 256;               // 79
  const int gy128 = Mpad / 128;               // 158

  char* ws = (char*)d_ws;
  size_t off = 0;
  auto alloc = [&](size_t bytes) -> char* {
    char* p = ws + off;
    off = (off + bytes + 255) & ~(size_t)255;
    return p;
  };
  int* flag = (int*)alloc(4);
  int* deg = (int*)alloc((size_t)M * 4);
  int* cursor = (int*)alloc((size_t)M * 4);
  int* rs = (int*)alloc((size_t)(M + 1) * 4);
  float* invdeg = (float*)alloc((size_t)M * 4);
  int* cs = (int*)alloc((size_t)E * 4);
  unsigned short* A1 = (unsigned short*)alloc((size_t)Mpad * 256 * 2);   // [mean(x)|x]
  unsigned short* h1 = (unsigned short*)alloc((size_t)Mpad * 1024 * 2);
  unsigned short* P2 = (unsigned short*)alloc((size_t)Mpad * 1024 * 2);  // [h1@w2_rel | h1@w2_root]
  unsigned short* h2 = (unsigned short*)alloc((size_t)Mpad * 512 * 2);
  float* P3 = (float*)alloc((size_t)Mpad * 128 * 4);                     // heads pre-agg
  unsigned short* Bt1 = (unsigned short*)alloc((size_t)H1 * 256 * 2);
  unsigned short* Bt2 = (unsigned short*)alloc((size_t)1024 * 1024 * 2);
  unsigned short* Bt3 = (unsigned short*)alloc((size_t)128 * 512 * 2);

  // CSR build
  init_kernel<<<64, 256, 0, stream>>>(deg, M, cursor, M, flag, (const long long*)edge, 2048, M);
  count_kernel<<<256, 256, 0, stream>>>(edge, E, flag, deg);
  scan_kernel<<<1, 1024, 0, stream>>>(deg, rs, invdeg, M);
  fill_kernel<<<256, 256, 0, stream>>>(edge, E, flag, rs, cursor, cs);

  // Weights (coalesced tiled transpose, one launch)
  wtrans_all_kernel<<<1344, 256, 0, stream>>>(w1_rel, w1_root, w2_rel, w2_root,
                                              wmu_rel, wmu_root, wls_rel, wls_root,
                                              Bt1, Bt2, Bt3);

  // Layer 1: A1 = [mean(x) | x] bf16; h1 = relu(A1 @ Bt1^T + b1)
  agg1_kernel<<<M, 128, 0, stream>>>(x, rs, cs, invdeg, A1);
  gemm256_kernel<<<(H1 / 256) * gy256, 512, 0, stream>>>(
      A1, 256, Bt1, 256, b1, h1, 1024, M, H1, 256, 1, 0, H1 / 256);

  // Layer 2 (commuted): P2 = h1 @ [w2_rel | w2_root]; h2 = relu(mean_agg(P2_rel) + P2_root + b2)
  gemm256_kernel<<<(1024 / 256) * gy256, 512, 0, stream>>>(
      h1, 1024, Bt2, 1024, nullptr, P2, 1024, M, 1024, 1024, 0, 0, 1024 / 256);
  agg2_kernel<<<M, 128, 0, stream>>>(P2, rs, cs, invdeg, b2, h2);

  // Heads (commuted): P3 = h2 @ [4 head mats]^T (fp32 out); out = mean_agg(P3_rel) + P3_root + bias
  gemm128_kernel<<<1 * gy128, 256, 0, stream>>>(
      h2, 512, Bt3, 512, nullptr, P3, 128, M, 128, 512, 0, 1, 1);
  float* outmu = (float*)d_out;
  float* outls = outmu + (size_t)M * 8;
  head_agg_kernel<<<(M * 16 + 255) / 256, 256, 0, stream>>>(
      P3, rs, cs, invdeg, bmu, bls, outmu, outls, M);
}

// Round 6
// 316.371 us; speedup vs baseline: 1.0228x; 1.0228x over previous
//
#include <hip/hip_runtime.h>

typedef __attribute__((ext_vector_type(8))) short short8;
typedef __attribute__((ext_vector_type(4))) float f32x4;
typedef unsigned long long u64;

__device__ __forceinline__ unsigned short f2bf(float f) {
  union { float f; unsigned u; } v; v.f = f;
  unsigned u = v.u;
  unsigned r = (u + 0x7FFFu + ((u >> 16) & 1u)) >> 16;  // RTNE
  return (unsigned short)r;
}
__device__ __forceinline__ float bf2f(unsigned short s) {
  union { unsigned u; float f; } v; v.u = ((unsigned)s) << 16;
  return v.f;
}

// async global->LDS, 16B per lane; LDS dest = wave-uniform base + lane*16
__device__ __forceinline__ void gl_lds16(const unsigned short* g, unsigned short* l) {
  __builtin_amdgcn_global_load_lds(
      (const __attribute__((address_space(1))) void*)g,
      (__attribute__((address_space(3))) void*)l, 16, 0, 0);
}

// ---------------- CSR build ----------------

__global__ void init_kernel(int* a, int n, int* b, int nb, int* flag,
                            const long long* edges, int nslots, int n_nodes) {
  int i = blockIdx.x * blockDim.x + threadIdx.x;
  int stride = gridDim.x * blockDim.x;
  for (int j = i; j < n; j += stride) a[j] = 0;
  for (int j = i; j < nb; j += stride) b[j] = 0;
  if (i == 0) *flag = 1;
  for (int j = i; j < nslots; j += stride) {
    long long v = edges[j];
    if (v < 0 || v >= n_nodes) atomicAnd(flag, 0);
  }
}

__device__ __forceinline__ int edge_at(const void* p, int is64, size_t idx) {
  return is64 ? (int)((const long long*)p)[idx] : ((const int*)p)[idx];
}

__global__ void count_kernel(const void* edges, int E, const int* flag, int* deg) {
  int is64 = *flag;
  int i = blockIdx.x * blockDim.x + threadIdx.x;
  int stride = gridDim.x * blockDim.x;
  for (int e = i; e < E; e += stride) {
    int d = edge_at(edges, is64, (size_t)E + e);
    atomicAdd(&deg[d], 1);
  }
}

__global__ void scan_kernel(const int* __restrict__ deg, int* __restrict__ rs,
                            float* __restrict__ invdeg, int n) {
  __shared__ int ssum[1024];
  int tid = threadIdx.x;
  int chunk = (n + 1023) >> 10;
  int start = tid * chunk;
  int end = min(start + chunk, n);
  int s = 0;
  for (int i = start; i < end; ++i) s += deg[i];
  ssum[tid] = s;
  __syncthreads();
  for (int off = 1; off < 1024; off <<= 1) {
    int t = (tid >= off) ? ssum[tid - off] : 0;
    __syncthreads();
    ssum[tid] += t;
    __syncthreads();
  }
  int run = (tid ? ssum[tid - 1] : 0);
  if (tid == 0) rs[0] = 0;
  for (int i = start; i < end; ++i) {
    int d = deg[i];
    run += d;
    rs[i + 1] = run;
    invdeg[i] = 1.0f / fmaxf((float)d, 1.0f);
  }
}

__global__ void fill_kernel(const void* edges, int E, const int* flag,
                            const int* __restrict__ rs, int* cursor, int* col_src) {
  int is64 = *flag;
  int i = blockIdx.x * blockDim.x + threadIdx.x;
  int stride = gridDim.x * blockDim.x;
  for (int e = i; e < E; e += stride) {
    int d = edge_at(edges, is64, (size_t)E + e);
    int s = edge_at(edges, is64, (size_t)e);
    int p = atomicAdd(&cursor[d], 1);
    col_src[rs[d] + p] = s;
  }
}

// ---------------- aggregation ----------------

__global__ void agg1_kernel(const float* __restrict__ x,
                            const int* __restrict__ rs, const int* __restrict__ cs,
                            const float* __restrict__ invdeg,
                            unsigned short* __restrict__ A1) {
  int node = blockIdx.x;
  int f = threadIdx.x;  // 128
  float xi = x[(size_t)node * 128 + f];
  float acc = 0.f;
  int e1 = rs[node + 1];
  for (int e = rs[node]; e < e1; ++e) {
    acc += x[(size_t)cs[e] * 128 + f];
  }
  A1[(size_t)node * 256 + f] = f2bf(acc * invdeg[node]);
  A1[(size_t)node * 256 + 128 + f] = f2bf(xi);
}

__global__ void agg2_kernel(const unsigned short* __restrict__ P2,
                            const int* __restrict__ rs, const int* __restrict__ cs,
                            const float* __restrict__ invdeg,
                            const float* __restrict__ b2,
                            unsigned short* __restrict__ h2) {
  int node = blockIdx.x;
  int f0 = threadIdx.x * 4;
  float acc0 = 0.f, acc1 = 0.f, acc2 = 0.f, acc3 = 0.f;
  int e1 = rs[node + 1];
  for (int e = rs[node]; e < e1; ++e) {
    int s = cs[e];
    u64 w = *reinterpret_cast<const u64*>(P2 + (size_t)s * 1024 + f0);
    acc0 += bf2f((unsigned short)w);
    acc1 += bf2f((unsigned short)(w >> 16));
    acc2 += bf2f((unsigned short)(w >> 32));
    acc3 += bf2f((unsigned short)(w >> 48));
  }
  float inv = invdeg[node];
  u64 wr = *reinterpret_cast<const u64*>(P2 + (size_t)node * 1024 + 512 + f0);
  float v0 = fmaxf(acc0 * inv + bf2f((unsigned short)wr) + b2[f0 + 0], 0.f);
  float v1 = fmaxf(acc1 * inv + bf2f((unsigned short)(wr >> 16)) + b2[f0 + 1], 0.f);
  float v2 = fmaxf(acc2 * inv + bf2f((unsigned short)(wr >> 32)) + b2[f0 + 2], 0.f);
  float v3 = fmaxf(acc3 * inv + bf2f((unsigned short)(wr >> 48)) + b2[f0 + 3], 0.f);
  u64 o = (u64)f2bf(v0) | ((u64)f2bf(v1) << 16) | ((u64)f2bf(v2) << 32) | ((u64)f2bf(v3) << 48);
  *reinterpret_cast<u64*>(h2 + (size_t)node * 512 + f0) = o;
}

__global__ void head_agg_kernel(const float* __restrict__ P3,
                                const int* __restrict__ rs, const int* __restrict__ cs,
                                const float* __restrict__ invdeg,
                                const float* __restrict__ bmu, const float* __restrict__ bls,
                                float* __restrict__ outmu, float* __restrict__ outls, int M) {
  int idx = blockIdx.x * blockDim.x + threadIdx.x;
  int node = idx >> 4;
  int c = idx & 15;
  if (node >= M) return;
  int relc = (c < 8) ? c : (16 + (c - 8));
  float acc = 0.f;
  int e1 = rs[node + 1];
  for (int e = rs[node]; e < e1; ++e) acc += P3[(size_t)cs[e] * 128 + relc];
  float v = acc * invdeg[node] + P3[(size_t)node * 128 + relc + 8]
          + ((c < 8) ? bmu[c] : bls[c - 8]);
  if (c < 8) outmu[(size_t)node * 8 + c] = v;
  else outls[(size_t)node * 8 + (c - 8)] = v;
}

// ---------------- weight transposes (LDS-tiled, coalesced) ----------------

__device__ __forceinline__ void ttile(const float* __restrict__ src, int Nw,
                                      unsigned short* __restrict__ dst, int ldd,
                                      int rowoff, int coloff,
                                      int tileIdx, int tilesN, float (*tile)[33]) {
  int tk = tileIdx / tilesN, tn = tileIdx % tilesN;
  int k0 = tk * 32, n0 = tn * 32;
  int tx = threadIdx.x & 31, ty = threadIdx.x >> 5;
#pragma unroll
  for (int s = 0; s < 4; ++s)
    tile[ty + s * 8][tx] = src[(size_t)(k0 + ty + s * 8) * Nw + n0 + tx];
  __syncthreads();
#pragma unroll
  for (int s = 0; s < 4; ++s)
    dst[(size_t)(rowoff + n0 + ty + s * 8) * ldd + coloff + k0 + tx] =
        f2bf(tile[tx][ty + s * 8]);
}

__global__ void wtrans_all_kernel(const float* __restrict__ w1_rel, const float* __restrict__ w1_root,
                                  const float* __restrict__ w2_rel, const float* __restrict__ w2_root,
                                  const float* __restrict__ wmu_rel, const float* __restrict__ wmu_root,
                                  const float* __restrict__ wls_rel, const float* __restrict__ wls_root,
                                  unsigned short* __restrict__ Bt1,
                                  unsigned short* __restrict__ Bt2,
                                  unsigned short* __restrict__ Bt3) {
  __shared__ float tile[32][33];
  int b = blockIdx.x;
  if (b < 128)       ttile(w1_rel, 1024, Bt1, 256, 0, 0, b, 32, tile);
  else if (b < 256)  ttile(w1_root, 1024, Bt1, 256, 0, 128, b - 128, 32, tile);
  else if (b < 768)  ttile(w2_rel, 512, Bt2, 1024, 0, 0, b - 256, 16, tile);
  else if (b < 1280) ttile(w2_root, 512, Bt2, 1024, 512, 0, b - 768, 16, tile);
  else {
    int idx = (b - 1280) * 256 + threadIdx.x;
    int n = idx >> 9, k = idx & 511;
    float v;
    if (n < 8) v = wmu_rel[(size_t)k * 8 + n];
    else if (n < 16) v = wmu_root[(size_t)k * 8 + (n - 8)];
    else if (n < 24) v = wls_rel[(size_t)k * 8 + (n - 16)];
    else v = wls_root[(size_t)k * 8 + (n - 24)];
    Bt3[(size_t)n * 512 + k] = f2bf(v);
  }
}

// ---------------- 8-phase 256x256 bf16 MFMA GEMM (T2+T3+T4+T5) ----------------
// C[M][N] = A[M][K] * Bt[N][K]^T (+bias)(relu). BM=BN=256, BK=64, 8 waves.
// LDS: [dbuf 2][mat 2][khalf 2] regions of [256 rows][4 slots of 16B] = 128 KiB.
// XOR swizzle (both-sides, rule #21): phys slot p at row r holds global slot
// p ^ ((r>>1)&3); staging pre-swizzles the GLOBAL source (LDS dest stays
// linear for global_load_lds); reads use slot lk ^ ((lr>>1)&3).
// Caller guarantees: Mpad256 rows readable in A, N%256==0, K%128==0, K>=256.
#define R_(d, mat, kh) ((((d) * 2 + (mat)) * 2 + (kh)) * 8192)

__launch_bounds__(512, 2)
__global__ void gemm256_kernel(const unsigned short* __restrict__ A, int lda,
                               const unsigned short* __restrict__ Bt, int ldb,
                               const float* __restrict__ bias,
                               void* __restrict__ outp, int ldo,
                               int M, int N, int K, int relu, int out_f32, int gx) {
  __shared__ unsigned short sh[65536];  // 128 KiB
  const int tid = threadIdx.x;
  const int lane = tid & 63;
  const int w = tid >> 6;              // 0..7
  const int wr = w >> 2, wc = w & 3;   // 2M x 4N wave grid; per-wave out 128x64
  const int lr = lane & 15, lk = lane >> 4;
  const int sw8 = (lk ^ ((lr >> 1) & 3)) * 8;  // swizzled read slot (shorts)
  const int wrb = (wr * 128 + lr) * 32;
  const int wcb = (wc * 64 + lr) * 32;

  // bijective XCD swizzle (m204)
  int nwg = gridDim.x, orig = blockIdx.x;
  int q = nwg >> 3, r = nwg & 7;
  int xcd = orig & 7, lid = orig >> 3;
  int swz = (xcd < r ? xcd * (q + 1) : r * (q + 1) + (xcd - r) * q) + lid;
  int m0 = (swz / gx) * 256, n0 = (swz % gx) * 256;

  f32x4 acc[8][4];
#pragma unroll
  for (int i = 0; i < 8; ++i)
#pragma unroll
    for (int j = 0; j < 4; ++j) acc[i][j] = (f32x4)0.0f;

  // staging thread map: row r4 = tid>>2 (0..127 per issue), phys slot s4 = tid&3;
  // fetch global slot slog = s4 ^ ((r4>>1)&3)  (rows r4 and r4+128 share the xor)
  const int r4 = tid >> 2, s4 = tid & 3;
  const int slog = s4 ^ ((r4 >> 1) & 3);
  const unsigned short* pA = A + (size_t)(m0 + r4) * lda + slog * 8;
  const unsigned short* pB = Bt + (size_t)(n0 + r4) * ldb + slog * 8;

  // stage one 256x32 region (= K-half of a K-tile): 2 global_load_lds issues
  auto STG = [&](int d, int mat, int kh, int kt) {
    const unsigned short* g = (mat ? pB : pA) + (size_t)kt * 64 + kh * 32;
    size_t ld = mat ? (size_t)ldb : (size_t)lda;
    unsigned short* lb = sh + R_(d, mat, kh) + w * 512;
    gl_lds16(g, lb);                       // rows 0..127 of region
    gl_lds16(g + 128 * ld, lb + 4096);     // rows 128..255
  };

  // prologue: T0 -> dbuf0, T1 -> dbuf1 (16 gloads); wait T0 (8 in flight)
  STG(0, 0, 0, 0); STG(0, 0, 1, 0); STG(0, 1, 0, 0); STG(0, 1, 1, 0);
  STG(1, 0, 0, 1); STG(1, 0, 1, 1); STG(1, 1, 0, 1); STG(1, 1, 1, 1);
  asm volatile("s_waitcnt vmcnt(8)" ::: "memory");
  __builtin_amdgcn_s_barrier();

#define DSB(dd, kk)                                                            \
  _Pragma("unroll") for (int nf = 0; nf < 4; ++nf)                             \
      bfr[nf] = *reinterpret_cast<const short8*>(                              \
          &sh[R_(dd, 1, kk) + wcb + nf * 512 + sw8]);

#define PH(dd, kk, mh, DOB, STGSTMT, ENDW)                                     \
  {                                                                            \
    if (DOB) { DSB(dd, kk) }                                                   \
    short8 af[4];                                                              \
    _Pragma("unroll") for (int mf = 0; mf < 4; ++mf)                           \
        af[mf] = *reinterpret_cast<const short8*>(                             \
            &sh[R_(dd, 0, kk) + wrb + mh * 2048 + mf * 512 + sw8]);            \
    STGSTMT;                                                                   \
    __builtin_amdgcn_s_barrier();                                              \
    asm volatile("s_waitcnt lgkmcnt(0)" ::: "memory");                         \
    __builtin_amdgcn_s_setprio(1);                                             \
    _Pragma("unroll") for (int mf = 0; mf < 4; ++mf)                           \
        _Pragma("unroll") for (int nf = 0; nf < 4; ++nf)                       \
            acc[mh * 4 + mf][nf] = __builtin_amdgcn_mfma_f32_16x16x32_bf16(    \
                af[mf], bfr[nf], acc[mh * 4 + mf][nf], 0, 0, 0);               \
    __builtin_amdgcn_s_setprio(0);                                             \
    ENDW;                                                                      \
    __builtin_amdgcn_s_barrier();                                              \
  }

  const int niter = K >> 7;  // K/128
  short8 bfr[4];
  for (int i = 0; i < niter; ++i) {
    const bool first = (i == 0), last = (i == niter - 1);
    const int t1 = 2 * i + 1, t2 = 2 * i + 2, t3 = 2 * i + 3;

    PH(0, 0, 0, 1, if (!first) { STG(1, 0, 1, t1); }, )
    PH(0, 0, 1, 0, if (!first) { STG(1, 1, 1, t1); },
       if (last) { asm volatile("s_waitcnt vmcnt(4)" ::: "memory"); }
       else      { asm volatile("s_waitcnt vmcnt(6)" ::: "memory"); })
    PH(0, 1, 0, 1, if (!last) { STG(0, 0, 0, t2); }, )
    PH(0, 1, 1, 0, if (!last) { STG(0, 1, 0, t2); },
       if (last) { asm volatile("s_waitcnt vmcnt(2)" ::: "memory"); }
       else      { asm volatile("s_waitcnt vmcnt(6)" ::: "memory"); })
    PH(1, 0, 0, 1, if (!last) { STG(0, 0, 1, t2); }, )
    PH(1, 0, 1, 0, if (!last) { STG(0, 1, 1, t2); },
       if (last) { asm volatile("s_waitcnt vmcnt(0)" ::: "memory"); }
       else      { asm volatile("s_waitcnt vmcnt(6)" ::: "memory"); })
    PH(1, 1, 0, 1, if (!last) { STG(1, 0, 0, t3); }, )
    PH(1, 1, 1, 0, if (!last) { STG(1, 1, 0, t3); },
       if (!last) { asm volatile("s_waitcnt vmcnt(6)" ::: "memory"); })
  }
#undef PH
#undef DSB

  // epilogue: C-write. frag C layout: col = lane&15, row = (lane>>4)*4 + rr
#pragma unroll
  for (int mf8 = 0; mf8 < 8; ++mf8) {
    int row_b = m0 + wr * 128 + mf8 * 16 + lk * 4;
#pragma unroll
    for (int nf = 0; nf < 4; ++nf) {
      int col = n0 + wc * 64 + nf * 16 + lr;
      float bv = bias ? bias[col] : 0.f;
#pragma unroll
      for (int rr = 0; rr < 4; ++rr) {
        int row = row_b + rr;
        if (row < M) {
          float v = acc[mf8][nf][rr] + bv;
          if (relu) v = fmaxf(v, 0.f);
          if (out_f32) ((float*)outp)[(size_t)row * ldo + col] = v;
          else ((unsigned short*)outp)[(size_t)row * ldo + col] = f2bf(v);
        }
      }
    }
  }
}

// ---------------- 128x128 ring GEMM (heads; small N) ----------------
__launch_bounds__(256, 3)
__global__ void gemm128_kernel(const unsigned short* __restrict__ A, int lda,
                               const unsigned short* __restrict__ Bt, int ldb,
                               const float* __restrict__ bias,
                               void* __restrict__ outp, int ldo,
                               int M, int N, int K, int relu, int out_f32, int gx) {
  __shared__ unsigned short As[3 * 4096];
  __shared__ unsigned short Bs[3 * 4096];
  int tid = threadIdx.x;
  int lane = tid & 63;
  int w = tid >> 6;
  int wr = w >> 1, wc = w & 1;
  int lr = lane & 15, lk = lane >> 4;

  int nwg = gridDim.x, orig = blockIdx.x;
  int q = nwg >> 3, r = nwg & 7;
  int xcd = orig & 7, lid = orig >> 3;
  int swz = (xcd < r ? xcd * (q + 1) : r * (q + 1) + (xcd - r) * q) + lid;
  int m0 = (swz / gx) * 128, n0 = (swz % gx) * 128;

  f32x4 acc[4][4];
#pragma unroll
  for (int i = 0; i < 4; ++i)
#pragma unroll
    for (int j = 0; j < 4; ++j) acc[i][j] = (f32x4)0.0f;

  int r0 = tid >> 2;
  int slog = (tid & 3) ^ ((r0 >> 1) & 3);
  const unsigned short* gA = A + (size_t)(m0 + r0) * lda + slog * 8;
  const unsigned short* gB = Bt + (size_t)(n0 + r0) * ldb + slog * 8;
  size_t a64 = (size_t)64 * lda, b64 = (size_t)64 * ldb;
  unsigned short* wa = As + w * 512;
  unsigned short* wb = Bs + w * 512;
  int sw8 = (lk ^ ((lr >> 1) & 3)) * 8;

  int nt = K >> 5;
  gl_lds16(gA, wa); gl_lds16(gA + a64, wa + 2048);
  gl_lds16(gB, wb); gl_lds16(gB + b64, wb + 2048);
  gA += 32; gB += 32;
  gl_lds16(gA, wa + 4096); gl_lds16(gA + a64, wa + 6144);
  gl_lds16(gB, wb + 4096); gl_lds16(gB + b64, wb + 6144);
  gA += 32; gB += 32;
  asm volatile("s_waitcnt vmcnt(4)" ::: "memory");
  __builtin_amdgcn_s_barrier();

  int bufR = 0, bufS = 2;
  for (int t = 0; t < nt; ++t) {
    if (t + 2 < nt) {
      unsigned short* sa = As + bufS * 4096 + w * 512;
      unsigned short* sb = Bs + bufS * 4096 + w * 512;
      gl_lds16(gA, sa); gl_lds16(gA + a64, sa + 2048);
      gl_lds16(gB, sb); gl_lds16(gB + b64, sb + 2048);
      gA += 32; gB += 32;
    }
    const unsigned short* as_ = As + bufR * 4096;
    const unsigned short* bs_ = Bs + bufR * 4096;
    short8 af[4], bfr[4];
#pragma unroll
    for (int i = 0; i < 4; ++i) {
      af[i]  = *reinterpret_cast<const short8*>(&as_[(wr * 64 + i * 16 + lr) * 32 + sw8]);
      bfr[i] = *reinterpret_cast<const short8*>(&bs_[(wc * 64 + i * 16 + lr) * 32 + sw8]);
    }
    __builtin_amdgcn_s_setprio(1);
#pragma unroll
    for (int i = 0; i < 4; ++i)
#pragma unroll
      for (int j = 0; j < 4; ++j)
        acc[i][j] = __builtin_amdgcn_mfma_f32_16x16x32_bf16(af[i], bfr[j], acc[i][j], 0, 0, 0);
    __builtin_amdgcn_s_setprio(0);
    if (t + 1 < nt) {
      if (t + 2 < nt)
        asm volatile("s_waitcnt vmcnt(4) lgkmcnt(0)" ::: "memory");
      else
        asm volatile("s_waitcnt vmcnt(0) lgkmcnt(0)" ::: "memory");
      __builtin_amdgcn_s_barrier();
    }
    bufR = (bufR == 2) ? 0 : bufR + 1;
    bufS = (bufS == 2) ? 0 : bufS + 1;
  }

#pragma unroll
  for (int i = 0; i < 4; ++i) {
    int row_b = m0 + wr * 64 + i * 16 + lk * 4;
#pragma unroll
    for (int j = 0; j < 4; ++j) {
      int col = n0 + wc * 64 + j * 16 + lr;
      float bv = bias ? bias[col] : 0.f;
#pragma unroll
      for (int rr = 0; rr < 4; ++rr) {
        int row = row_b + rr;
        if (row < M) {
          float v = acc[i][j][rr] + bv;
          if (relu) v = fmaxf(v, 0.f);
          if (out_f32) ((float*)outp)[(size_t)row * ldo + col] = v;
          else ((unsigned short*)outp)[(size_t)row * ldo + col] = f2bf(v);
        }
      }
    }
  }
}

// ---------------- host ----------------

extern "C" void kernel_launch(void* const* d_in, const int* in_sizes, int n_in,
                              void* d_out, int out_size, void* d_ws, size_t ws_size,
                              hipStream_t stream) {
  const float* x = (const float*)d_in[0];
  const void* edge = d_in[1];
  const float* w1_rel = (const float*)d_in[2];
  const float* b1 = (const float*)d_in[3];
  const float* w1_root = (const float*)d_in[4];
  const float* w2_rel = (const float*)d_in[5];
  const float* b2 = (const float*)d_in[6];
  const float* w2_root = (const float*)d_in[7];
  const float* wmu_rel = (const float*)d_in[8];
  const float* bmu = (const float*)d_in[9];
  const float* wmu_root = (const float*)d_in[10];
  const float* wls_rel = (const float*)d_in[11];
  const float* bls = (const float*)d_in[12];
  const float* wls_root = (const float*)d_in[13];

  const int FIN = 128, H1 = 1024, H2 = 512;
  const int M = in_sizes[0] / FIN;   // 20000
  const int E = in_sizes[1] / 2;     // 160000
  const int Mpad = ((M + 255) / 256) * 256;   // 20224
  const int gy256 = Mpad / 256;               // 79
  const int gy128 = Mpad / 128;               // 158

  char* ws = (char*)d_ws;
  size_t off = 0;
  auto alloc = [&](size_t bytes) -> char* {
    char* p = ws + off;
    off = (off + bytes + 255) & ~(size_t)255;
    return p;
  };
  int* flag = (int*)alloc(4);
  int* deg = (int*)alloc((size_t)M * 4);
  int* cursor = (int*)alloc((size_t)M * 4);
  int* rs = (int*)alloc((size_t)(M + 1) * 4);
  float* invdeg = (float*)alloc((size_t)M * 4);
  int* cs = (int*)alloc((size_t)E * 4);
  unsigned short* A1 = (unsigned short*)alloc((size_t)Mpad * 256 * 2);   // [mean(x)|x]
  unsigned short* h1 = (unsigned short*)alloc((size_t)Mpad * 1024 * 2);
  unsigned short* P2 = (unsigned short*)alloc((size_t)Mpad * 1024 * 2);  // [h1@w2_rel | h1@w2_root]
  unsigned short* h2 = (unsigned short*)alloc((size_t)Mpad * 512 * 2);
  float* P3 = (float*)alloc((size_t)Mpad * 128 * 4);                     // heads pre-agg
  unsigned short* Bt1 = (unsigned short*)alloc((size_t)H1 * 256 * 2);
  unsigned short* Bt2 = (unsigned short*)alloc((size_t)1024 * 1024 * 2);
  unsigned short* Bt3 = (unsigned short*)alloc((size_t)128 * 512 * 2);

  // CSR build
  init_kernel<<<64, 256, 0, stream>>>(deg, M, cursor, M, flag, (const long long*)edge, 2048, M);
  count_kernel<<<256, 256, 0, stream>>>(edge, E, flag, deg);
  scan_kernel<<<1, 1024, 0, stream>>>(deg, rs, invdeg, M);
  fill_kernel<<<256, 256, 0, stream>>>(edge, E, flag, rs, cursor, cs);

  // Weights (coalesced tiled transpose, one launch)
  wtrans_all_kernel<<<1344, 256, 0, stream>>>(w1_rel, w1_root, w2_rel, w2_root,
                                              wmu_rel, wmu_root, wls_rel, wls_root,
                                              Bt1, Bt2, Bt3);

  // Layer 1: A1 = [mean(x) | x] bf16; h1 = relu(A1 @ Bt1^T + b1)
  agg1_kernel<<<M, 128, 0, stream>>>(x, rs, cs, invdeg, A1);
  gemm256_kernel<<<(H1 / 256) * gy256, 512, 0, stream>>>(
      A1, 256, Bt1, 256, b1, h1, 1024, M, H1, 256, 1, 0, H1 / 256);

  // Layer 2 (commuted): P2 = h1 @ [w2_rel | w2_root]; h2 = relu(mean_agg(P2_rel) + P2_root + b2)
  gemm256_kernel<<<(1024 / 256) * gy256, 512, 0, stream>>>(
      h1, 1024, Bt2, 1024, nullptr, P2, 1024, M, 1024, 1024, 0, 0, 1024 / 256);
  agg2_kernel<<<M, 128, 0, stream>>>(P2, rs, cs, invdeg, b2, h2);

  // Heads (commuted): P3 = h2 @ [4 head mats]^T (fp32 out); out = mean_agg(P3_rel) + P3_root + bias
  gemm128_kernel<<<1 * gy128, 256, 0, stream>>>(
      h2, 512, Bt3, 512, nullptr, P3, 128, M, 128, 512, 0, 1, 1);
  float* outmu = (float*)d_out;
  float* outls = outmu + (size_t)M * 8;
  head_agg_kernel<<<(M * 16 + 255) / 256, 256, 0, stream>>>(
      P3, rs, cs, invdeg, bmu, bls, outmu, outls, M);
}

// Round 7
// 315.523 us; speedup vs baseline: 1.0255x; 1.0027x over previous
//
#include <hip/hip_runtime.h>

typedef __attribute__((ext_vector_type(8))) short short8;
typedef __attribute__((ext_vector_type(4))) float f32x4;
typedef unsigned long long u64;

__device__ __forceinline__ unsigned short f2bf(float f) {
  union { float f; unsigned u; } v; v.f = f;
  unsigned u = v.u;
  unsigned r = (u + 0x7FFFu + ((u >> 16) & 1u)) >> 16;  // RTNE
  return (unsigned short)r;
}
__device__ __forceinline__ float bf2f(unsigned short s) {
  union { unsigned u; float f; } v; v.u = ((unsigned)s) << 16;
  return v.f;
}

// async global->LDS, 16B per lane; LDS dest = wave-uniform base + lane*16
__device__ __forceinline__ void gl_lds16(const unsigned short* g, unsigned short* l) {
  __builtin_amdgcn_global_load_lds(
      (const __attribute__((address_space(1))) void*)g,
      (__attribute__((address_space(3))) void*)l, 16, 0, 0);
}

// ---------------- CSR build ----------------

__global__ void init_kernel(int* a, int n, int* b, int nb, int* flag,
                            const long long* edges, int nslots, int n_nodes) {
  int i = blockIdx.x * blockDim.x + threadIdx.x;
  int stride = gridDim.x * blockDim.x;
  for (int j = i; j < n; j += stride) a[j] = 0;
  for (int j = i; j < nb; j += stride) b[j] = 0;
  if (i == 0) *flag = 1;
  for (int j = i; j < nslots; j += stride) {
    long long v = edges[j];
    if (v < 0 || v >= n_nodes) atomicAnd(flag, 0);
  }
}

__device__ __forceinline__ int edge_at(const void* p, int is64, size_t idx) {
  return is64 ? (int)((const long long*)p)[idx] : ((const int*)p)[idx];
}

__global__ void count_kernel(const void* edges, int E, const int* flag, int* deg) {
  int is64 = *flag;
  int i = blockIdx.x * blockDim.x + threadIdx.x;
  int stride = gridDim.x * blockDim.x;
  for (int e = i; e < E; e += stride) {
    int d = edge_at(edges, is64, (size_t)E + e);
    atomicAdd(&deg[d], 1);
  }
}

__global__ void scan_kernel(const int* __restrict__ deg, int* __restrict__ rs,
                            float* __restrict__ invdeg, int n) {
  __shared__ int ssum[1024];
  int tid = threadIdx.x;
  int chunk = (n + 1023) >> 10;
  int start = tid * chunk;
  int end = min(start + chunk, n);
  int s = 0;
  for (int i = start; i < end; ++i) s += deg[i];
  ssum[tid] = s;
  __syncthreads();
  for (int off = 1; off < 1024; off <<= 1) {
    int t = (tid >= off) ? ssum[tid - off] : 0;
    __syncthreads();
    ssum[tid] += t;
    __syncthreads();
  }
  int run = (tid ? ssum[tid - 1] : 0);
  if (tid == 0) rs[0] = 0;
  for (int i = start; i < end; ++i) {
    int d = deg[i];
    run += d;
    rs[i + 1] = run;
    invdeg[i] = 1.0f / fmaxf((float)d, 1.0f);
  }
}

__global__ void fill_kernel(const void* edges, int E, const int* flag,
                            const int* __restrict__ rs, int* cursor, int* col_src) {
  int is64 = *flag;
  int i = blockIdx.x * blockDim.x + threadIdx.x;
  int stride = gridDim.x * blockDim.x;
  for (int e = i; e < E; e += stride) {
    int d = edge_at(edges, is64, (size_t)E + e);
    int s = edge_at(edges, is64, (size_t)e);
    int p = atomicAdd(&cursor[d], 1);
    col_src[rs[d] + p] = s;
  }
}

// ---------------- aggregation ----------------

__global__ void agg1_kernel(const float* __restrict__ x,
                            const int* __restrict__ rs, const int* __restrict__ cs,
                            const float* __restrict__ invdeg,
                            unsigned short* __restrict__ A1) {
  int node = blockIdx.x;
  int f = threadIdx.x;  // 128
  float xi = x[(size_t)node * 128 + f];
  float acc = 0.f;
  int e1 = rs[node + 1];
  for (int e = rs[node]; e < e1; ++e) {
    acc += x[(size_t)cs[e] * 128 + f];
  }
  A1[(size_t)node * 256 + f] = f2bf(acc * invdeg[node]);
  A1[(size_t)node * 256 + 128 + f] = f2bf(xi);
}

__global__ void agg2_kernel(const unsigned short* __restrict__ P2,
                            const int* __restrict__ rs, const int* __restrict__ cs,
                            const float* __restrict__ invdeg,
                            const float* __restrict__ b2,
                            unsigned short* __restrict__ h2) {
  int node = blockIdx.x;
  int f0 = threadIdx.x * 4;
  float acc0 = 0.f, acc1 = 0.f, acc2 = 0.f, acc3 = 0.f;
  int e1 = rs[node + 1];
  for (int e = rs[node]; e < e1; ++e) {
    int s = cs[e];
    u64 w = *reinterpret_cast<const u64*>(P2 + (size_t)s * 1024 + f0);
    acc0 += bf2f((unsigned short)w);
    acc1 += bf2f((unsigned short)(w >> 16));
    acc2 += bf2f((unsigned short)(w >> 32));
    acc3 += bf2f((unsigned short)(w >> 48));
  }
  float inv = invdeg[node];
  u64 wr = *reinterpret_cast<const u64*>(P2 + (size_t)node * 1024 + 512 + f0);
  float v0 = fmaxf(acc0 * inv + bf2f((unsigned short)wr) + b2[f0 + 0], 0.f);
  float v1 = fmaxf(acc1 * inv + bf2f((unsigned short)(wr >> 16)) + b2[f0 + 1], 0.f);
  float v2 = fmaxf(acc2 * inv + bf2f((unsigned short)(wr >> 32)) + b2[f0 + 2], 0.f);
  float v3 = fmaxf(acc3 * inv + bf2f((unsigned short)(wr >> 48)) + b2[f0 + 3], 0.f);
  u64 o = (u64)f2bf(v0) | ((u64)f2bf(v1) << 16) | ((u64)f2bf(v2) << 32) | ((u64)f2bf(v3) << 48);
  *reinterpret_cast<u64*>(h2 + (size_t)node * 512 + f0) = o;
}

__global__ void head_agg_kernel(const float* __restrict__ P3,
                                const int* __restrict__ rs, const int* __restrict__ cs,
                                const float* __restrict__ invdeg,
                                const float* __restrict__ bmu, const float* __restrict__ bls,
                                float* __restrict__ outmu, float* __restrict__ outls, int M) {
  int idx = blockIdx.x * blockDim.x + threadIdx.x;
  int node = idx >> 4;
  int c = idx & 15;
  if (node >= M) return;
  int relc = (c < 8) ? c : (16 + (c - 8));
  float acc = 0.f;
  int e1 = rs[node + 1];
  for (int e = rs[node]; e < e1; ++e) acc += P3[(size_t)cs[e] * 128 + relc];
  float v = acc * invdeg[node] + P3[(size_t)node * 128 + relc + 8]
          + ((c < 8) ? bmu[c] : bls[c - 8]);
  if (c < 8) outmu[(size_t)node * 8 + c] = v;
  else outls[(size_t)node * 8 + (c - 8)] = v;
}

// ---------------- weight transposes (LDS-tiled, coalesced) ----------------

__device__ __forceinline__ void ttile(const float* __restrict__ src, int Nw,
                                      unsigned short* __restrict__ dst, int ldd,
                                      int rowoff, int coloff,
                                      int tileIdx, int tilesN, float (*tile)[33]) {
  int tk = tileIdx / tilesN, tn = tileIdx % tilesN;
  int k0 = tk * 32, n0 = tn * 32;
  int tx = threadIdx.x & 31, ty = threadIdx.x >> 5;
#pragma unroll
  for (int s = 0; s < 4; ++s)
    tile[ty + s * 8][tx] = src[(size_t)(k0 + ty + s * 8) * Nw + n0 + tx];
  __syncthreads();
#pragma unroll
  for (int s = 0; s < 4; ++s)
    dst[(size_t)(rowoff + n0 + ty + s * 8) * ldd + coloff + k0 + tx] =
        f2bf(tile[tx][ty + s * 8]);
}

__global__ void wtrans_all_kernel(const float* __restrict__ w1_rel, const float* __restrict__ w1_root,
                                  const float* __restrict__ w2_rel, const float* __restrict__ w2_root,
                                  const float* __restrict__ wmu_rel, const float* __restrict__ wmu_root,
                                  const float* __restrict__ wls_rel, const float* __restrict__ wls_root,
                                  unsigned short* __restrict__ Bt1,
                                  unsigned short* __restrict__ Bt2,
                                  unsigned short* __restrict__ Bt3) {
  __shared__ float tile[32][33];
  int b = blockIdx.x;
  if (b < 128)       ttile(w1_rel, 1024, Bt1, 256, 0, 0, b, 32, tile);
  else if (b < 256)  ttile(w1_root, 1024, Bt1, 256, 0, 128, b - 128, 32, tile);
  else if (b < 768)  ttile(w2_rel, 512, Bt2, 1024, 0, 0, b - 256, 16, tile);
  else if (b < 1280) ttile(w2_root, 512, Bt2, 1024, 512, 0, b - 768, 16, tile);
  else {
    int idx = (b - 1280) * 256 + threadIdx.x;
    int n = idx >> 9, k = idx & 511;
    float v;
    if (n < 8) v = wmu_rel[(size_t)k * 8 + n];
    else if (n < 16) v = wmu_root[(size_t)k * 8 + (n - 8)];
    else if (n < 24) v = wls_rel[(size_t)k * 8 + (n - 16)];
    else v = wls_root[(size_t)k * 8 + (n - 24)];
    Bt3[(size_t)n * 512 + k] = f2bf(v);
  }
}

// ---- 8-phase 256x256 bf16 MFMA GEMM, register-pipelined (T2+T3+T4+T5) ----
// C[M][N] = A[M][K] * Bt[N][K]^T (+bias)(relu). BM=BN=256, BK=64, 8 waves.
// LDS regions [dbuf2][mat2][khalf2] of [256 rows][4 x 16B slots] (128 KiB).
// Slot-XOR swizzle (both-sides): staging pre-swizzles the GLOBAL source slot,
// reads use slot lk^((lr>>1)&3). Fragment reads for phase p+1 are issued in
// phase p (double-buffered registers) so ds_read/global_load_lds/MFMA overlap;
// one barrier per phase; vmcnt(6) at odd phase ends only.
// Region staging map per iter i (a..h), verified vmcnt FIFO invariant:
//  ph1:a=(1,A,1,t1) ph2:b=(1,B,1,t1) ph3:c=(0,A,0,t2) ph4:d=(0,B,0,t2)
//  ph5:e=(0,A,1,t2) ph6:f=(0,B,1,t2) ph7:g=(1,A,0,t3) ph8:h=(1,B,0,t3)
// Caller guarantees: Mpad256 rows readable, N%256==0, K%128==0, K>=256.
#define R_(d, mat, kh) ((((d) * 2 + (mat)) * 2 + (kh)) * 8192)

__launch_bounds__(512, 2)
__global__ void gemm256_kernel(const unsigned short* __restrict__ A, int lda,
                               const unsigned short* __restrict__ Bt, int ldb,
                               const float* __restrict__ bias,
                               void* __restrict__ outp, int ldo,
                               int M, int N, int K, int relu, int out_f32, int gx) {
  __shared__ unsigned short sh[65536];  // 128 KiB
  const int tid = threadIdx.x;
  const int lane = tid & 63;
  const int w = tid >> 6;              // 0..7
  const int wr = w >> 2, wc = w & 3;   // 2M x 4N wave grid; per-wave out 128x64
  const int lr = lane & 15, lk = lane >> 4;
  const int sw8 = (lk ^ ((lr >> 1) & 3)) * 8;  // swizzled read slot (shorts)
  const int wrb = (wr * 128 + lr) * 32;
  const int wcb = (wc * 64 + lr) * 32;

  // bijective XCD swizzle (m204)
  int nwg = gridDim.x, orig = blockIdx.x;
  int q = nwg >> 3, r = nwg & 7;
  int xcd = orig & 7, lid = orig >> 3;
  int swz = (xcd < r ? xcd * (q + 1) : r * (q + 1) + (xcd - r) * q) + lid;
  int m0 = (swz / gx) * 256, n0 = (swz % gx) * 256;

  f32x4 acc[8][4];
#pragma unroll
  for (int i = 0; i < 8; ++i)
#pragma unroll
    for (int j = 0; j < 4; ++j) acc[i][j] = (f32x4)0.0f;

  // staging: row r4 = tid>>2, phys slot s4 = tid&3; fetch global slot
  // slog = s4 ^ ((r4>>1)&3)  (rows r4 and r4+128 share the xor term)
  const int r4 = tid >> 2, s4 = tid & 3;
  const int slog = s4 ^ ((r4 >> 1) & 3);
  const unsigned short* pA = A + (size_t)(m0 + r4) * lda + slog * 8;
  const unsigned short* pB = Bt + (size_t)(n0 + r4) * ldb + slog * 8;

  // stage one 256x32 region: 2 global_load_lds per thread (+2 vmcnt per wave)
  auto STG = [&](int d, int mat, int kh, int kt) {
    const unsigned short* g = (mat ? pB : pA) + (size_t)kt * 64 + kh * 32;
    size_t ld = mat ? (size_t)ldb : (size_t)lda;
    unsigned short* lb = sh + R_(d, mat, kh) + w * 512;
    gl_lds16(g, lb);
    gl_lds16(g + 128 * ld, lb + 4096);
  };

#define LDA4(dst, dd, kk, mh)                                                  \
  _Pragma("unroll") for (int mf = 0; mf < 4; ++mf)                             \
      dst[mf] = *reinterpret_cast<const short8*>(                              \
          &sh[R_(dd, 0, kk) + wrb + (mh) * 2048 + mf * 512 + sw8]);

#define LDB4(dst, dd, kk)                                                      \
  _Pragma("unroll") for (int nf = 0; nf < 4; ++nf)                             \
      dst[nf] = *reinterpret_cast<const short8*>(                              \
          &sh[R_(dd, 1, kk) + wcb + nf * 512 + sw8]);

#define MFMA16(A_, B_, mh)                                                     \
  __builtin_amdgcn_s_setprio(1);                                               \
  _Pragma("unroll") for (int mf = 0; mf < 4; ++mf)                             \
      _Pragma("unroll") for (int nf = 0; nf < 4; ++nf)                         \
          acc[(mh) * 4 + mf][nf] = __builtin_amdgcn_mfma_f32_16x16x32_bf16(    \
              A_[mf], B_[nf], acc[(mh) * 4 + mf][nf], 0, 0, 0);                \
  __builtin_amdgcn_s_setprio(0);

#define BAR __builtin_amdgcn_s_barrier()
#define VMC(n) asm volatile("s_waitcnt vmcnt(" #n ")" ::: "memory")

  // prologue: stage T0 fully (c,d,e,f) + T1 kh0 (g,h) = 12 loads/wave;
  // drain to 8 -> regions c,d landed; pre-read phase-1 fragments.
  STG(0, 0, 0, 0); STG(0, 1, 0, 0); STG(0, 0, 1, 0); STG(0, 1, 1, 0);
  STG(1, 0, 0, 1); STG(1, 1, 0, 1);
  VMC(8);
  BAR;

  short8 afA[4], afB[4], bfA[4], bfB[4];
  LDA4(afA, 0, 0, 0);
  LDB4(bfA, 0, 0);

  const int niter = K >> 7;  // K/128, >= 2
  for (int i = 0; i < niter; ++i) {
    const bool last = (i == niter - 1);
    const int t1 = 2 * i + 1, t2 = 2 * i + 2, t3 = 2 * i + 3;

    // ph1: compute (0,kk0,mh0); ahead af for ph2
    LDA4(afB, 0, 0, 1);
    STG(1, 0, 1, t1);
    MFMA16(afA, bfA, 0);
    VMC(6); BAR;
    // ph2: (0,kk0,mh1); ahead af+bf for ph3
    LDA4(afA, 0, 1, 0); LDB4(bfB, 0, 1);
    STG(1, 1, 1, t1);
    MFMA16(afB, bfA, 1);
    BAR;
    // ph3: (0,kk1,mh0); ahead af for ph4
    LDA4(afB, 0, 1, 1);
    if (!last) { STG(0, 0, 0, t2); }
    MFMA16(afA, bfB, 0);
    if (last) { VMC(4); } else { VMC(6); }
    BAR;
    // ph4: (0,kk1,mh1); ahead af+bf for ph5
    LDA4(afA, 1, 0, 0); LDB4(bfA, 1, 0);
    if (!last) { STG(0, 1, 0, t2); }
    MFMA16(afB, bfB, 1);
    BAR;
    // ph5: (1,kk0,mh0); ahead af for ph6
    LDA4(afB, 1, 0, 1);
    if (!last) { STG(0, 0, 1, t2); }
    MFMA16(afA, bfA, 0);
    if (last) { VMC(0); } else { VMC(6); }
    BAR;
    // ph6: (1,kk0,mh1); ahead af+bf for ph7
    LDA4(afA, 1, 1, 0); LDB4(bfB, 1, 1);
    if (!last) { STG(0, 1, 1, t2); }
    MFMA16(afB, bfA, 1);
    BAR;
    // ph7: (1,kk1,mh0); ahead af for ph8
    LDA4(afB, 1, 1, 1);
    if (!last) { STG(1, 0, 0, t3); }
    MFMA16(afA, bfB, 0);
    if (!last) { VMC(6); }
    BAR;
    // ph8: (1,kk1,mh1); ahead af+bf for next-iter ph1
    if (!last) {
      LDA4(afA, 0, 0, 0); LDB4(bfA, 0, 0);
      STG(1, 1, 0, t3);
    }
    MFMA16(afB, bfB, 1);
    BAR;
  }
#undef LDA4
#undef LDB4
#undef MFMA16
#undef BAR
#undef VMC

  // epilogue: C-write. frag C layout: col = lane&15, row = (lane>>4)*4 + rr
#pragma unroll
  for (int mf8 = 0; mf8 < 8; ++mf8) {
    int row_b = m0 + wr * 128 + mf8 * 16 + lk * 4;
#pragma unroll
    for (int nf = 0; nf < 4; ++nf) {
      int col = n0 + wc * 64 + nf * 16 + lr;
      float bv = bias ? bias[col] : 0.f;
#pragma unroll
      for (int rr = 0; rr < 4; ++rr) {
        int row = row_b + rr;
        if (row < M) {
          float v = acc[mf8][nf][rr] + bv;
          if (relu) v = fmaxf(v, 0.f);
          if (out_f32) ((float*)outp)[(size_t)row * ldo + col] = v;
          else ((unsigned short*)outp)[(size_t)row * ldo + col] = f2bf(v);
        }
      }
    }
  }
}

// ---------------- 128x128 ring GEMM (heads; small N) ----------------
__launch_bounds__(256, 3)
__global__ void gemm128_kernel(const unsigned short* __restrict__ A, int lda,
                               const unsigned short* __restrict__ Bt, int ldb,
                               const float* __restrict__ bias,
                               void* __restrict__ outp, int ldo,
                               int M, int N, int K, int relu, int out_f32, int gx) {
  __shared__ unsigned short As[3 * 4096];
  __shared__ unsigned short Bs[3 * 4096];
  int tid = threadIdx.x;
  int lane = tid & 63;
  int w = tid >> 6;
  int wr = w >> 1, wc = w & 1;
  int lr = lane & 15, lk = lane >> 4;

  int nwg = gridDim.x, orig = blockIdx.x;
  int q = nwg >> 3, r = nwg & 7;
  int xcd = orig & 7, lid = orig >> 3;
  int swz = (xcd < r ? xcd * (q + 1) : r * (q + 1) + (xcd - r) * q) + lid;
  int m0 = (swz / gx) * 128, n0 = (swz % gx) * 128;

  f32x4 acc[4][4];
#pragma unroll
  for (int i = 0; i < 4; ++i)
#pragma unroll
    for (int j = 0; j < 4; ++j) acc[i][j] = (f32x4)0.0f;

  int r0 = tid >> 2;
  int slog = (tid & 3) ^ ((r0 >> 1) & 3);
  const unsigned short* gA = A + (size_t)(m0 + r0) * lda + slog * 8;
  const unsigned short* gB = Bt + (size_t)(n0 + r0) * ldb + slog * 8;
  size_t a64 = (size_t)64 * lda, b64 = (size_t)64 * ldb;
  unsigned short* wa = As + w * 512;
  unsigned short* wb = Bs + w * 512;
  int sw8 = (lk ^ ((lr >> 1) & 3)) * 8;

  int nt = K >> 5;
  gl_lds16(gA, wa); gl_lds16(gA + a64, wa + 2048);
  gl_lds16(gB, wb); gl_lds16(gB + b64, wb + 2048);
  gA += 32; gB += 32;
  gl_lds16(gA, wa + 4096); gl_lds16(gA + a64, wa + 6144);
  gl_lds16(gB, wb + 4096); gl_lds16(gB + b64, wb + 6144);
  gA += 32; gB += 32;
  asm volatile("s_waitcnt vmcnt(4)" ::: "memory");
  __builtin_amdgcn_s_barrier();

  int bufR = 0, bufS = 2;
  for (int t = 0; t < nt; ++t) {
    if (t + 2 < nt) {
      unsigned short* sa = As + bufS * 4096 + w * 512;
      unsigned short* sb = Bs + bufS * 4096 + w * 512;
      gl_lds16(gA, sa); gl_lds16(gA + a64, sa + 2048);
      gl_lds16(gB, sb); gl_lds16(gB + b64, sb + 2048);
      gA += 32; gB += 32;
    }
    const unsigned short* as_ = As + bufR * 4096;
    const unsigned short* bs_ = Bs + bufR * 4096;
    short8 af[4], bfr[4];
#pragma unroll
    for (int i = 0; i < 4; ++i) {
      af[i]  = *reinterpret_cast<const short8*>(&as_[(wr * 64 + i * 16 + lr) * 32 + sw8]);
      bfr[i] = *reinterpret_cast<const short8*>(&bs_[(wc * 64 + i * 16 + lr) * 32 + sw8]);
    }
    __builtin_amdgcn_s_setprio(1);
#pragma unroll
    for (int i = 0; i < 4; ++i)
#pragma unroll
      for (int j = 0; j < 4; ++j)
        acc[i][j] = __builtin_amdgcn_mfma_f32_16x16x32_bf16(af[i], bfr[j], acc[i][j], 0, 0, 0);
    __builtin_amdgcn_s_setprio(0);
    if (t + 1 < nt) {
      if (t + 2 < nt)
        asm volatile("s_waitcnt vmcnt(4) lgkmcnt(0)" ::: "memory");
      else
        asm volatile("s_waitcnt vmcnt(0) lgkmcnt(0)" ::: "memory");
      __builtin_amdgcn_s_barrier();
    }
    bufR = (bufR == 2) ? 0 : bufR + 1;
    bufS = (bufS == 2) ? 0 : bufS + 1;
  }

#pragma unroll
  for (int i = 0; i < 4; ++i) {
    int row_b = m0 + wr * 64 + i * 16 + lk * 4;
#pragma unroll
    for (int j = 0; j < 4; ++j) {
      int col = n0 + wc * 64 + j * 16 + lr;
      float bv = bias ? bias[col] : 0.f;
#pragma unroll
      for (int rr = 0; rr < 4; ++rr) {
        int row = row_b + rr;
        if (row < M) {
          float v = acc[i][j][rr] + bv;
          if (relu) v = fmaxf(v, 0.f);
          if (out_f32) ((float*)outp)[(size_t)row * ldo + col] = v;
          else ((unsigned short*)outp)[(size_t)row * ldo + col] = f2bf(v);
        }
      }
    }
  }
}

// ---------------- host ----------------

extern "C" void kernel_launch(void* const* d_in, const int* in_sizes, int n_in,
                              void* d_out, int out_size, void* d_ws, size_t ws_size,
                              hipStream_t stream) {
  const float* x = (const float*)d_in[0];
  const void* edge = d_in[1];
  const float* w1_rel = (const float*)d_in[2];
  const float* b1 = (const float*)d_in[3];
  const float* w1_root = (const float*)d_in[4];
  const float* w2_rel = (const float*)d_in[5];
  const float* b2 = (const float*)d_in[6];
  const float* w2_root = (const float*)d_in[7];
  const float* wmu_rel = (const float*)d_in[8];
  const float* bmu = (const float*)d_in[9];
  const float* wmu_root = (const float*)d_in[10];
  const float* wls_rel = (const float*)d_in[11];
  const float* bls = (const float*)d_in[12];
  const float* wls_root = (const float*)d_in[13];

  const int FIN = 128, H1 = 1024, H2 = 512;
  const int M = in_sizes[0] / FIN;   // 20000
  const int E = in_sizes[1] / 2;     // 160000
  const int Mpad = ((M + 255) / 256) * 256;   // 20224
  const int gy256 = Mpad / 256;               // 79
  const int gy128 = Mpad / 128;               // 158

  char* ws = (char*)d_ws;
  size_t off = 0;
  auto alloc = [&](size_t bytes) -> char* {
    char* p = ws + off;
    off = (off + bytes + 255) & ~(size_t)255;
    return p;
  };
  int* flag = (int*)alloc(4);
  int* deg = (int*)alloc((size_t)M * 4);
  int* cursor = (int*)alloc((size_t)M * 4);
  int* rs = (int*)alloc((size_t)(M + 1) * 4);
  float* invdeg = (float*)alloc((size_t)M * 4);
  int* cs = (int*)alloc((size_t)E * 4);
  unsigned short* A1 = (unsigned short*)alloc((size_t)Mpad * 256 * 2);   // [mean(x)|x]
  unsigned short* h1 = (unsigned short*)alloc((size_t)Mpad * 1024 * 2);
  unsigned short* P2 = (unsigned short*)alloc((size_t)Mpad * 1024 * 2);  // [h1@w2_rel | h1@w2_root]
  unsigned short* h2 = (unsigned short*)alloc((size_t)Mpad * 512 * 2);
  float* P3 = (float*)alloc((size_t)Mpad * 128 * 4);                     // heads pre-agg
  unsigned short* Bt1 = (unsigned short*)alloc((size_t)H1 * 256 * 2);
  unsigned short* Bt2 = (unsigned short*)alloc((size_t)1024 * 1024 * 2);
  unsigned short* Bt3 = (unsigned short*)alloc((size_t)128 * 512 * 2);

  // CSR build
  init_kernel<<<64, 256, 0, stream>>>(deg, M, cursor, M, flag, (const long long*)edge, 2048, M);
  count_kernel<<<256, 256, 0, stream>>>(edge, E, flag, deg);
  scan_kernel<<<1, 1024, 0, stream>>>(deg, rs, invdeg, M);
  fill_kernel<<<256, 256, 0, stream>>>(edge, E, flag, rs, cursor, cs);

  // Weights (coalesced tiled transpose, one launch)
  wtrans_all_kernel<<<1344, 256, 0, stream>>>(w1_rel, w1_root, w2_rel, w2_root,
                                              wmu_rel, wmu_root, wls_rel, wls_root,
                                              Bt1, Bt2, Bt3);

  // Layer 1: A1 = [mean(x) | x] bf16; h1 = relu(A1 @ Bt1^T + b1)
  agg1_kernel<<<M, 128, 0, stream>>>(x, rs, cs, invdeg, A1);
  gemm256_kernel<<<(H1 / 256) * gy256, 512, 0, stream>>>(
      A1, 256, Bt1, 256, b1, h1, 1024, M, H1, 256, 1, 0, H1 / 256);

  // Layer 2 (commuted): P2 = h1 @ [w2_rel | w2_root]; h2 = relu(mean_agg(P2_rel) + P2_root + b2)
  gemm256_kernel<<<(1024 / 256) * gy256, 512, 0, stream>>>(
      h1, 1024, Bt2, 1024, nullptr, P2, 1024, M, 1024, 1024, 0, 0, 1024 / 256);
  agg2_kernel<<<M, 128, 0, stream>>>(P2, rs, cs, invdeg, b2, h2);

  // Heads (commuted): P3 = h2 @ [4 head mats]^T (fp32 out); out = mean_agg(P3_rel) + P3_root + bias
  gemm128_kernel<<<1 * gy128, 256, 0, stream>>>(
      h2, 512, Bt3, 512, nullptr, P3, 128, M, 128, 512, 0, 1, 1);
  float* outmu = (float*)d_out;
  float* outls = outmu + (size_t)M * 8;
  head_agg_kernel<<<(M * 16 + 255) / 256, 256, 0, stream>>>(
      P3, rs, cs, invdeg, bmu, bls, outmu, outls, M);
}

// Round 8
// 284.107 us; speedup vs baseline: 1.1389x; 1.1106x over previous
//
#include <hip/hip_runtime.h>

typedef __attribute__((ext_vector_type(8))) short short8;
typedef __attribute__((ext_vector_type(4))) float f32x4;
typedef unsigned long long u64;

__device__ __forceinline__ unsigned short f2bf(float f) {
  union { float f; unsigned u; } v; v.f = f;
  unsigned u = v.u;
  unsigned r = (u + 0x7FFFu + ((u >> 16) & 1u)) >> 16;  // RTNE
  return (unsigned short)r;
}
__device__ __forceinline__ float bf2f(unsigned short s) {
  union { unsigned u; float f; } v; v.u = ((unsigned)s) << 16;
  return v.f;
}

// async global->LDS, 16B per lane; LDS dest = wave-uniform base + lane*16
__device__ __forceinline__ void gl_lds16(const unsigned short* g, unsigned short* l) {
  __builtin_amdgcn_global_load_lds(
      (const __attribute__((address_space(1))) void*)g,
      (__attribute__((address_space(3))) void*)l, 16, 0, 0);
}

// ---------------- CSR build ----------------

__global__ void init_kernel(int* a, int n, int* b, int nb, int* flag,
                            const long long* edges, int nslots, int n_nodes) {
  int i = blockIdx.x * blockDim.x + threadIdx.x;
  int stride = gridDim.x * blockDim.x;
  for (int j = i; j < n; j += stride) a[j] = 0;
  for (int j = i; j < nb; j += stride) b[j] = 0;
  if (i == 0) *flag = 1;
  for (int j = i; j < nslots; j += stride) {
    long long v = edges[j];
    if (v < 0 || v >= n_nodes) atomicAnd(flag, 0);
  }
}

__device__ __forceinline__ int edge_at(const void* p, int is64, size_t idx) {
  return is64 ? (int)((const long long*)p)[idx] : ((const int*)p)[idx];
}

__global__ void count_kernel(const void* edges, int E, const int* flag, int* deg) {
  int is64 = *flag;
  int i = blockIdx.x * blockDim.x + threadIdx.x;
  int stride = gridDim.x * blockDim.x;
  for (int e = i; e < E; e += stride) {
    int d = edge_at(edges, is64, (size_t)E + e);
    atomicAdd(&deg[d], 1);
  }
}

__global__ void scan_kernel(const int* __restrict__ deg, int* __restrict__ rs,
                            float* __restrict__ invdeg, int n) {
  __shared__ int ssum[1024];
  int tid = threadIdx.x;
  int chunk = (n + 1023) >> 10;
  int start = tid * chunk;
  int end = min(start + chunk, n);
  int s = 0;
  for (int i = start; i < end; ++i) s += deg[i];
  ssum[tid] = s;
  __syncthreads();
  for (int off = 1; off < 1024; off <<= 1) {
    int t = (tid >= off) ? ssum[tid - off] : 0;
    __syncthreads();
    ssum[tid] += t;
    __syncthreads();
  }
  int run = (tid ? ssum[tid - 1] : 0);
  if (tid == 0) rs[0] = 0;
  for (int i = start; i < end; ++i) {
    int d = deg[i];
    run += d;
    rs[i + 1] = run;
    invdeg[i] = 1.0f / fmaxf((float)d, 1.0f);
  }
}

__global__ void fill_kernel(const void* edges, int E, const int* flag,
                            const int* __restrict__ rs, int* cursor, int* col_src) {
  int is64 = *flag;
  int i = blockIdx.x * blockDim.x + threadIdx.x;
  int stride = gridDim.x * blockDim.x;
  for (int e = i; e < E; e += stride) {
    int d = edge_at(edges, is64, (size_t)E + e);
    int s = edge_at(edges, is64, (size_t)e);
    int p = atomicAdd(&cursor[d], 1);
    col_src[rs[d] + p] = s;
  }
}

// ---------------- aggregation ----------------

__global__ void agg1_kernel(const float* __restrict__ x,
                            const int* __restrict__ rs, const int* __restrict__ cs,
                            const float* __restrict__ invdeg,
                            unsigned short* __restrict__ A1) {
  int node = blockIdx.x;
  int f = threadIdx.x;  // 128
  float xi = x[(size_t)node * 128 + f];
  float acc = 0.f;
  int e1 = rs[node + 1];
  for (int e = rs[node]; e < e1; ++e) {
    acc += x[(size_t)cs[e] * 128 + f];
  }
  A1[(size_t)node * 256 + f] = f2bf(acc * invdeg[node]);
  A1[(size_t)node * 256 + 128 + f] = f2bf(xi);
}

__global__ void agg2_kernel(const unsigned short* __restrict__ P2,
                            const int* __restrict__ rs, const int* __restrict__ cs,
                            const float* __restrict__ invdeg,
                            const float* __restrict__ b2,
                            unsigned short* __restrict__ h2) {
  int node = blockIdx.x;
  int f0 = threadIdx.x * 4;
  float acc0 = 0.f, acc1 = 0.f, acc2 = 0.f, acc3 = 0.f;
  int e1 = rs[node + 1];
  for (int e = rs[node]; e < e1; ++e) {
    int s = cs[e];
    u64 w = *reinterpret_cast<const u64*>(P2 + (size_t)s * 1024 + f0);
    acc0 += bf2f((unsigned short)w);
    acc1 += bf2f((unsigned short)(w >> 16));
    acc2 += bf2f((unsigned short)(w >> 32));
    acc3 += bf2f((unsigned short)(w >> 48));
  }
  float inv = invdeg[node];
  u64 wr = *reinterpret_cast<const u64*>(P2 + (size_t)node * 1024 + 512 + f0);
  float v0 = fmaxf(acc0 * inv + bf2f((unsigned short)wr) + b2[f0 + 0], 0.f);
  float v1 = fmaxf(acc1 * inv + bf2f((unsigned short)(wr >> 16)) + b2[f0 + 1], 0.f);
  float v2 = fmaxf(acc2 * inv + bf2f((unsigned short)(wr >> 32)) + b2[f0 + 2], 0.f);
  float v3 = fmaxf(acc3 * inv + bf2f((unsigned short)(wr >> 48)) + b2[f0 + 3], 0.f);
  u64 o = (u64)f2bf(v0) | ((u64)f2bf(v1) << 16) | ((u64)f2bf(v2) << 32) | ((u64)f2bf(v3) << 48);
  *reinterpret_cast<u64*>(h2 + (size_t)node * 512 + f0) = o;
}

__global__ void head_agg_kernel(const float* __restrict__ P3,
                                const int* __restrict__ rs, const int* __restrict__ cs,
                                const float* __restrict__ invdeg,
                                const float* __restrict__ bmu, const float* __restrict__ bls,
                                float* __restrict__ outmu, float* __restrict__ outls, int M) {
  int idx = blockIdx.x * blockDim.x + threadIdx.x;
  int node = idx >> 4;
  int c = idx & 15;
  if (node >= M) return;
  int relc = (c < 8) ? c : (16 + (c - 8));
  float acc = 0.f;
  int e1 = rs[node + 1];
  for (int e = rs[node]; e < e1; ++e) acc += P3[(size_t)cs[e] * 128 + relc];
  float v = acc * invdeg[node] + P3[(size_t)node * 128 + relc + 8]
          + ((c < 8) ? bmu[c] : bls[c - 8]);
  if (c < 8) outmu[(size_t)node * 8 + c] = v;
  else outls[(size_t)node * 8 + (c - 8)] = v;
}

// ---------------- weight transposes (LDS-tiled, coalesced) ----------------

__device__ __forceinline__ void ttile(const float* __restrict__ src, int Nw,
                                      unsigned short* __restrict__ dst, int ldd,
                                      int rowoff, int coloff,
                                      int tileIdx, int tilesN, float (*tile)[33]) {
  int tk = tileIdx / tilesN, tn = tileIdx % tilesN;
  int k0 = tk * 32, n0 = tn * 32;
  int tx = threadIdx.x & 31, ty = threadIdx.x >> 5;
#pragma unroll
  for (int s = 0; s < 4; ++s)
    tile[ty + s * 8][tx] = src[(size_t)(k0 + ty + s * 8) * Nw + n0 + tx];
  __syncthreads();
#pragma unroll
  for (int s = 0; s < 4; ++s)
    dst[(size_t)(rowoff + n0 + ty + s * 8) * ldd + coloff + k0 + tx] =
        f2bf(tile[tx][ty + s * 8]);
}

__global__ void wtrans_all_kernel(const float* __restrict__ w1_rel, const float* __restrict__ w1_root,
                                  const float* __restrict__ w2_rel, const float* __restrict__ w2_root,
                                  const float* __restrict__ wmu_rel, const float* __restrict__ wmu_root,
                                  const float* __restrict__ wls_rel, const float* __restrict__ wls_root,
                                  unsigned short* __restrict__ Bt1,
                                  unsigned short* __restrict__ Bt2,
                                  unsigned short* __restrict__ Bt3) {
  __shared__ float tile[32][33];
  int b = blockIdx.x;
  if (b < 128)       ttile(w1_rel, 1024, Bt1, 256, 0, 0, b, 32, tile);
  else if (b < 256)  ttile(w1_root, 1024, Bt1, 256, 0, 128, b - 128, 32, tile);
  else if (b < 768)  ttile(w2_rel, 512, Bt2, 1024, 0, 0, b - 256, 16, tile);
  else if (b < 1280) ttile(w2_root, 512, Bt2, 1024, 512, 0, b - 768, 16, tile);
  else {
    int idx = (b - 1280) * 256 + threadIdx.x;
    int n = idx >> 9, k = idx & 511;
    float v;
    if (n < 8) v = wmu_rel[(size_t)k * 8 + n];
    else if (n < 16) v = wmu_root[(size_t)k * 8 + (n - 8)];
    else if (n < 24) v = wls_rel[(size_t)k * 8 + (n - 16)];
    else v = wls_root[(size_t)k * 8 + (n - 24)];
    Bt3[(size_t)n * 512 + k] = f2bf(v);
  }
}

// ------- 128x256 ring GEMM, 8 waves, ring-3 LDS, counted vmcnt, swizzled -------
// C[M][N] = A[M][K] * Bt[N][K]^T (+bias)(relu). BM=128, BN=256, BK=32.
// Waves: 2(M) x 4(N); per-wave output 64x64 (acc[4][4] = 64 VGPR).
// LDS ring of 3 slots: slot = A[128][32] (8 KB) + B[256][32] (16 KB) = 24 KB;
// 72 KB total -> 2 blocks/CU; 16 waves/CU at ~110 VGPR (TLP is the lever).
// Both-sides slot-XOR swizzle (global-source pre-swizzle + swizzled ds_read).
// Caller: Mpad128 rows readable, N%256==0, K%32==0, K>=64.
__launch_bounds__(512, 4)
__global__ void gemm_wide_kernel(const unsigned short* __restrict__ A, int lda,
                                 const unsigned short* __restrict__ Bt, int ldb,
                                 const float* __restrict__ bias,
                                 void* __restrict__ outp, int ldo,
                                 int M, int N, int K, int relu, int out_f32, int gx) {
  __shared__ unsigned short As[3 * 4096];   // 3 x [128][32]
  __shared__ unsigned short Bs[3 * 8192];   // 3 x [256][32]
  const int tid = threadIdx.x;
  const int lane = tid & 63;
  const int w = tid >> 6;             // 0..7
  const int wr = w >> 2, wc = w & 3;  // 2M x 4N
  const int lr = lane & 15, lk = lane >> 4;
  const int sw8 = (lk ^ ((lr >> 1) & 3)) * 8;  // swizzled read slot (shorts)

  // bijective XCD swizzle (m204)
  int nwg = gridDim.x, orig = blockIdx.x;
  int q = nwg >> 3, r = nwg & 7;
  int xcd = orig & 7, lid = orig >> 3;
  int swz = (xcd < r ? xcd * (q + 1) : r * (q + 1) + (xcd - r) * q) + lid;
  int m0 = (swz / gx) * 128, n0 = (swz % gx) * 256;

  f32x4 acc[4][4];
#pragma unroll
  for (int i = 0; i < 4; ++i)
#pragma unroll
    for (int j = 0; j < 4; ++j) acc[i][j] = (f32x4)0.0f;

  // staging map: row r0 = tid>>2 (0..127), phys slot s4 = tid&3,
  // global slot slog = s4 ^ ((r0>>1)&3)  (row+128 shares the xor term)
  const int r0 = tid >> 2;
  const int slog = ((tid & 3) ^ ((r0 >> 1) & 3)) * 8;
  const unsigned short* gA = A + (size_t)(m0 + r0) * lda + slog;
  const unsigned short* gB = Bt + (size_t)(n0 + r0) * ldb + slog;
  size_t b128 = (size_t)128 * ldb;
  unsigned short* wa = As + w * 512;   // per-wave 1 KB share of A slot
  unsigned short* wb = Bs + w * 512;   // per-wave shares of B slot (2 x 1 KB)

  // stage K-tile t into ring slot s: 3 gl_lds per thread (A:1, B:2)
  auto STG = [&](int s, int t) {
    const unsigned short* a = gA + (size_t)t * 32;
    const unsigned short* b = gB + (size_t)t * 32;
    gl_lds16(a, wa + s * 4096);
    gl_lds16(b, wb + s * 8192);
    gl_lds16(b + b128, wb + s * 8192 + 4096);
  };

  int nt = K >> 5;  // >= 2
  STG(0, 0);
  STG(1, 1);
  asm volatile("s_waitcnt vmcnt(3)" ::: "memory");  // tile 0 landed; tile 1 flying
  __builtin_amdgcn_s_barrier();

  int bufR = 0, bufS = 2;
  for (int t = 0; t < nt; ++t) {
    if (t + 2 < nt) STG(bufS, t + 2);
    const unsigned short* as_ = As + bufR * 4096;
    const unsigned short* bs_ = Bs + bufR * 8192;
    short8 af[4], bf[4];
#pragma unroll
    for (int i = 0; i < 4; ++i) {
      af[i] = *reinterpret_cast<const short8*>(&as_[(wr * 64 + i * 16 + lr) * 32 + sw8]);
      bf[i] = *reinterpret_cast<const short8*>(&bs_[(wc * 64 + i * 16 + lr) * 32 + sw8]);
    }
    __builtin_amdgcn_s_setprio(1);
#pragma unroll
    for (int i = 0; i < 4; ++i)
#pragma unroll
      for (int j = 0; j < 4; ++j)
        acc[i][j] = __builtin_amdgcn_mfma_f32_16x16x32_bf16(af[i], bf[j], acc[i][j], 0, 0, 0);
    __builtin_amdgcn_s_setprio(0);
    if (t + 1 < nt) {
      if (t + 2 < nt)
        asm volatile("s_waitcnt vmcnt(3) lgkmcnt(0)" ::: "memory");  // t+1 landed; t+2 flying
      else
        asm volatile("s_waitcnt vmcnt(0) lgkmcnt(0)" ::: "memory");
      __builtin_amdgcn_s_barrier();
    }
    bufR = (bufR == 2) ? 0 : bufR + 1;
    bufS = (bufS == 2) ? 0 : bufS + 1;
  }

#pragma unroll
  for (int i = 0; i < 4; ++i) {
    int row_b = m0 + wr * 64 + i * 16 + lk * 4;
#pragma unroll
    for (int j = 0; j < 4; ++j) {
      int col = n0 + wc * 64 + j * 16 + lr;
      float bv = bias ? bias[col] : 0.f;
#pragma unroll
      for (int rr = 0; rr < 4; ++rr) {
        int row = row_b + rr;
        if (row < M) {
          float v = acc[i][j][rr] + bv;
          if (relu) v = fmaxf(v, 0.f);
          if (out_f32) ((float*)outp)[(size_t)row * ldo + col] = v;
          else ((unsigned short*)outp)[(size_t)row * ldo + col] = f2bf(v);
        }
      }
    }
  }
}

// ---------------- 128x128 ring GEMM (heads; small N) ----------------
__launch_bounds__(256, 3)
__global__ void gemm128_kernel(const unsigned short* __restrict__ A, int lda,
                               const unsigned short* __restrict__ Bt, int ldb,
                               const float* __restrict__ bias,
                               void* __restrict__ outp, int ldo,
                               int M, int N, int K, int relu, int out_f32, int gx) {
  __shared__ unsigned short As[3 * 4096];
  __shared__ unsigned short Bs[3 * 4096];
  int tid = threadIdx.x;
  int lane = tid & 63;
  int w = tid >> 6;
  int wr = w >> 1, wc = w & 1;
  int lr = lane & 15, lk = lane >> 4;

  int nwg = gridDim.x, orig = blockIdx.x;
  int q = nwg >> 3, r = nwg & 7;
  int xcd = orig & 7, lid = orig >> 3;
  int swz = (xcd < r ? xcd * (q + 1) : r * (q + 1) + (xcd - r) * q) + lid;
  int m0 = (swz / gx) * 128, n0 = (swz % gx) * 128;

  f32x4 acc[4][4];
#pragma unroll
  for (int i = 0; i < 4; ++i)
#pragma unroll
    for (int j = 0; j < 4; ++j) acc[i][j] = (f32x4)0.0f;

  int r0 = tid >> 2;
  int slog = (tid & 3) ^ ((r0 >> 1) & 3);
  const unsigned short* gA = A + (size_t)(m0 + r0) * lda + slog * 8;
  const unsigned short* gB = Bt + (size_t)(n0 + r0) * ldb + slog * 8;
  size_t a64 = (size_t)64 * lda, b64 = (size_t)64 * ldb;
  unsigned short* wa = As + w * 512;
  unsigned short* wb = Bs + w * 512;
  int sw8 = (lk ^ ((lr >> 1) & 3)) * 8;

  int nt = K >> 5;
  gl_lds16(gA, wa); gl_lds16(gA + a64, wa + 2048);
  gl_lds16(gB, wb); gl_lds16(gB + b64, wb + 2048);
  gA += 32; gB += 32;
  gl_lds16(gA, wa + 4096); gl_lds16(gA + a64, wa + 6144);
  gl_lds16(gB, wb + 4096); gl_lds16(gB + b64, wb + 6144);
  gA += 32; gB += 32;
  asm volatile("s_waitcnt vmcnt(4)" ::: "memory");
  __builtin_amdgcn_s_barrier();

  int bufR = 0, bufS = 2;
  for (int t = 0; t < nt; ++t) {
    if (t + 2 < nt) {
      unsigned short* sa = As + bufS * 4096 + w * 512;
      unsigned short* sb = Bs + bufS * 4096 + w * 512;
      gl_lds16(gA, sa); gl_lds16(gA + a64, sa + 2048);
      gl_lds16(gB, sb); gl_lds16(gB + b64, sb + 2048);
      gA += 32; gB += 32;
    }
    const unsigned short* as_ = As + bufR * 4096;
    const unsigned short* bs_ = Bs + bufR * 4096;
    short8 af[4], bfr[4];
#pragma unroll
    for (int i = 0; i < 4; ++i) {
      af[i]  = *reinterpret_cast<const short8*>(&as_[(wr * 64 + i * 16 + lr) * 32 + sw8]);
      bfr[i] = *reinterpret_cast<const short8*>(&bs_[(wc * 64 + i * 16 + lr) * 32 + sw8]);
    }
    __builtin_amdgcn_s_setprio(1);
#pragma unroll
    for (int i = 0; i < 4; ++i)
#pragma unroll
      for (int j = 0; j < 4; ++j)
        acc[i][j] = __builtin_amdgcn_mfma_f32_16x16x32_bf16(af[i], bfr[j], acc[i][j], 0, 0, 0);
    __builtin_amdgcn_s_setprio(0);
    if (t + 1 < nt) {
      if (t + 2 < nt)
        asm volatile("s_waitcnt vmcnt(4) lgkmcnt(0)" ::: "memory");
      else
        asm volatile("s_waitcnt vmcnt(0) lgkmcnt(0)" ::: "memory");
      __builtin_amdgcn_s_barrier();
    }
    bufR = (bufR == 2) ? 0 : bufR + 1;
    bufS = (bufS == 2) ? 0 : bufS + 1;
  }

#pragma unroll
  for (int i = 0; i < 4; ++i) {
    int row_b = m0 + wr * 64 + i * 16 + lk * 4;
#pragma unroll
    for (int j = 0; j < 4; ++j) {
      int col = n0 + wc * 64 + j * 16 + lr;
      float bv = bias ? bias[col] : 0.f;
#pragma unroll
      for (int rr = 0; rr < 4; ++rr) {
        int row = row_b + rr;
        if (row < M) {
          float v = acc[i][j][rr] + bv;
          if (relu) v = fmaxf(v, 0.f);
          if (out_f32) ((float*)outp)[(size_t)row * ldo + col] = v;
          else ((unsigned short*)outp)[(size_t)row * ldo + col] = f2bf(v);
        }
      }
    }
  }
}

// ---------------- host ----------------

extern "C" void kernel_launch(void* const* d_in, const int* in_sizes, int n_in,
                              void* d_out, int out_size, void* d_ws, size_t ws_size,
                              hipStream_t stream) {
  const float* x = (const float*)d_in[0];
  const void* edge = d_in[1];
  const float* w1_rel = (const float*)d_in[2];
  const float* b1 = (const float*)d_in[3];
  const float* w1_root = (const float*)d_in[4];
  const float* w2_rel = (const float*)d_in[5];
  const float* b2 = (const float*)d_in[6];
  const float* w2_root = (const float*)d_in[7];
  const float* wmu_rel = (const float*)d_in[8];
  const float* bmu = (const float*)d_in[9];
  const float* wmu_root = (const float*)d_in[10];
  const float* wls_rel = (const float*)d_in[11];
  const float* bls = (const float*)d_in[12];
  const float* wls_root = (const float*)d_in[13];

  const int FIN = 128, H1 = 1024, H2 = 512;
  const int M = in_sizes[0] / FIN;   // 20000
  const int E = in_sizes[1] / 2;     // 160000
  const int Mpad = ((M + 127) / 128) * 128;   // 20096
  const int gy = Mpad / 128;                  // 157

  char* ws = (char*)d_ws;
  size_t off = 0;
  auto alloc = [&](size_t bytes) -> char* {
    char* p = ws + off;
    off = (off + bytes + 255) & ~(size_t)255;
    return p;
  };
  int* flag = (int*)alloc(4);
  int* deg = (int*)alloc((size_t)M * 4);
  int* cursor = (int*)alloc((size_t)M * 4);
  int* rs = (int*)alloc((size_t)(M + 1) * 4);
  float* invdeg = (float*)alloc((size_t)M * 4);
  int* cs = (int*)alloc((size_t)E * 4);
  unsigned short* A1 = (unsigned short*)alloc((size_t)Mpad * 256 * 2);   // [mean(x)|x]
  unsigned short* h1 = (unsigned short*)alloc((size_t)Mpad * 1024 * 2);
  unsigned short* P2 = (unsigned short*)alloc((size_t)Mpad * 1024 * 2);  // [h1@w2_rel | h1@w2_root]
  unsigned short* h2 = (unsigned short*)alloc((size_t)Mpad * 512 * 2);
  float* P3 = (float*)alloc((size_t)Mpad * 128 * 4);                     // heads pre-agg
  unsigned short* Bt1 = (unsigned short*)alloc((size_t)H1 * 256 * 2);
  unsigned short* Bt2 = (unsigned short*)alloc((size_t)1024 * 1024 * 2);
  unsigned short* Bt3 = (unsigned short*)alloc((size_t)128 * 512 * 2);

  // CSR build
  init_kernel<<<64, 256, 0, stream>>>(deg, M, cursor, M, flag, (const long long*)edge, 2048, M);
  count_kernel<<<256, 256, 0, stream>>>(edge, E, flag, deg);
  scan_kernel<<<1, 1024, 0, stream>>>(deg, rs, invdeg, M);
  fill_kernel<<<256, 256, 0, stream>>>(edge, E, flag, rs, cursor, cs);

  // Weights (coalesced tiled transpose, one launch)
  wtrans_all_kernel<<<1344, 256, 0, stream>>>(w1_rel, w1_root, w2_rel, w2_root,
                                              wmu_rel, wmu_root, wls_rel, wls_root,
                                              Bt1, Bt2, Bt3);

  // Layer 1: A1 = [mean(x) | x] bf16; h1 = relu(A1 @ Bt1^T + b1)
  agg1_kernel<<<M, 128, 0, stream>>>(x, rs, cs, invdeg, A1);
  gemm_wide_kernel<<<(H1 / 256) * gy, 512, 0, stream>>>(
      A1, 256, Bt1, 256, b1, h1, 1024, M, H1, 256, 1, 0, H1 / 256);

  // Layer 2 (commuted): P2 = h1 @ [w2_rel | w2_root]; h2 = relu(mean_agg(P2_rel) + P2_root + b2)
  gemm_wide_kernel<<<(1024 / 256) * gy, 512, 0, stream>>>(
      h1, 1024, Bt2, 1024, nullptr, P2, 1024, M, 1024, 1024, 0, 0, 1024 / 256);
  agg2_kernel<<<M, 128, 0, stream>>>(P2, rs, cs, invdeg, b2, h2);

  // Heads (commuted): P3 = h2 @ [4 head mats]^T (fp32 out); out = mean_agg(P3_rel) + P3_root + bias
  gemm128_kernel<<<1 * gy, 256, 0, stream>>>(
      h2, 512, Bt3, 512, nullptr, P3, 128, M, 128, 512, 0, 1, 1);
  float* outmu = (float*)d_out;
  float* outls = outmu + (size_t)M * 8;
  head_agg_kernel<<<(M * 16 + 255) / 256, 256, 0, stream>>>(
      P3, rs, cs, invdeg, bmu, bls, outmu, outls, M);
}

// Round 9
// 281.265 us; speedup vs baseline: 1.1505x; 1.0101x over previous
//
#include <hip/hip_runtime.h>

typedef __attribute__((ext_vector_type(8))) short short8;
typedef __attribute__((ext_vector_type(4))) float f32x4;
typedef unsigned long long u64;

__device__ __forceinline__ unsigned short f2bf(float f) {
  union { float f; unsigned u; } v; v.f = f;
  unsigned u = v.u;
  unsigned r = (u + 0x7FFFu + ((u >> 16) & 1u)) >> 16;  // RTNE
  return (unsigned short)r;
}
__device__ __forceinline__ float bf2f(unsigned short s) {
  union { unsigned u; float f; } v; v.u = ((unsigned)s) << 16;
  return v.f;
}

// async global->LDS, 16B per lane; LDS dest = wave-uniform base + lane*16
__device__ __forceinline__ void gl_lds16(const unsigned short* g, unsigned short* l) {
  __builtin_amdgcn_global_load_lds(
      (const __attribute__((address_space(1))) void*)g,
      (__attribute__((address_space(3))) void*)l, 16, 0, 0);
}

// ---------------- CSR build ----------------

__global__ void init_kernel(int* a, int n, int* b, int nb, int* flag,
                            const long long* edges, int nslots, int n_nodes) {
  int i = blockIdx.x * blockDim.x + threadIdx.x;
  int stride = gridDim.x * blockDim.x;
  for (int j = i; j < n; j += stride) a[j] = 0;
  for (int j = i; j < nb; j += stride) b[j] = 0;
  if (i == 0) *flag = 1;
  for (int j = i; j < nslots; j += stride) {
    long long v = edges[j];
    if (v < 0 || v >= n_nodes) atomicAnd(flag, 0);
  }
}

__device__ __forceinline__ int edge_at(const void* p, int is64, size_t idx) {
  return is64 ? (int)((const long long*)p)[idx] : ((const int*)p)[idx];
}

__global__ void count_kernel(const void* edges, int E, const int* flag, int* deg) {
  int is64 = *flag;
  int i = blockIdx.x * blockDim.x + threadIdx.x;
  int stride = gridDim.x * blockDim.x;
  for (int e = i; e < E; e += stride) {
    int d = edge_at(edges, is64, (size_t)E + e);
    atomicAdd(&deg[d], 1);
  }
}

__global__ void scan_kernel(const int* __restrict__ deg, int* __restrict__ rs,
                            float* __restrict__ invdeg, int n) {
  __shared__ int ssum[1024];
  int tid = threadIdx.x;
  int chunk = (n + 1023) >> 10;
  int start = tid * chunk;
  int end = min(start + chunk, n);
  int s = 0;
  for (int i = start; i < end; ++i) s += deg[i];
  ssum[tid] = s;
  __syncthreads();
  for (int off = 1; off < 1024; off <<= 1) {
    int t = (tid >= off) ? ssum[tid - off] : 0;
    __syncthreads();
    ssum[tid] += t;
    __syncthreads();
  }
  int run = (tid ? ssum[tid - 1] : 0);
  if (tid == 0) rs[0] = 0;
  for (int i = start; i < end; ++i) {
    int d = deg[i];
    run += d;
    rs[i + 1] = run;
    invdeg[i] = 1.0f / fmaxf((float)d, 1.0f);
  }
}

__global__ void fill_kernel(const void* edges, int E, const int* flag,
                            const int* __restrict__ rs, int* cursor, int* col_src) {
  int is64 = *flag;
  int i = blockIdx.x * blockDim.x + threadIdx.x;
  int stride = gridDim.x * blockDim.x;
  for (int e = i; e < E; e += stride) {
    int d = edge_at(edges, is64, (size_t)E + e);
    int s = edge_at(edges, is64, (size_t)e);
    int p = atomicAdd(&cursor[d], 1);
    col_src[rs[d] + p] = s;
  }
}

// ---------------- aggregation ----------------

__global__ void agg1_kernel(const float* __restrict__ x,
                            const int* __restrict__ rs, const int* __restrict__ cs,
                            const float* __restrict__ invdeg,
                            unsigned short* __restrict__ A1) {
  int node = blockIdx.x;
  int f = threadIdx.x;  // 128
  float xi = x[(size_t)node * 128 + f];
  float acc = 0.f;
  int e1 = rs[node + 1];
  for (int e = rs[node]; e < e1; ++e) {
    acc += x[(size_t)cs[e] * 128 + f];
  }
  A1[(size_t)node * 256 + f] = f2bf(acc * invdeg[node]);
  A1[(size_t)node * 256 + 128 + f] = f2bf(xi);
}

// layer-2 combine, 2 nodes/block, 16B per lane:
// h2[i][c] = relu( inv*sum_j P2[j][c] + P2[i][512+c] + b2[c] )
__global__ void agg2_kernel(const unsigned short* __restrict__ P2,
                            const int* __restrict__ rs, const int* __restrict__ cs,
                            const float* __restrict__ invdeg,
                            const float* __restrict__ b2,
                            unsigned short* __restrict__ h2, int M) {
  int node = blockIdx.x * 2 + (threadIdx.x >> 6);
  if (node >= M) return;
  int f0 = (threadIdx.x & 63) * 8;  // 64 lanes x 8 cols = 512
  float acc[8];
#pragma unroll
  for (int v = 0; v < 8; ++v) acc[v] = 0.f;
  int e1 = rs[node + 1];
  for (int e = rs[node]; e < e1; ++e) {
    int s = cs[e];
    uint4 w = *reinterpret_cast<const uint4*>(P2 + (size_t)s * 1024 + f0);
    acc[0] += bf2f((unsigned short)(w.x & 0xffff));
    acc[1] += bf2f((unsigned short)(w.x >> 16));
    acc[2] += bf2f((unsigned short)(w.y & 0xffff));
    acc[3] += bf2f((unsigned short)(w.y >> 16));
    acc[4] += bf2f((unsigned short)(w.z & 0xffff));
    acc[5] += bf2f((unsigned short)(w.z >> 16));
    acc[6] += bf2f((unsigned short)(w.w & 0xffff));
    acc[7] += bf2f((unsigned short)(w.w >> 16));
  }
  float inv = invdeg[node];
  uint4 wr = *reinterpret_cast<const uint4*>(P2 + (size_t)node * 1024 + 512 + f0);
  float rt[8] = {
    bf2f((unsigned short)(wr.x & 0xffff)), bf2f((unsigned short)(wr.x >> 16)),
    bf2f((unsigned short)(wr.y & 0xffff)), bf2f((unsigned short)(wr.y >> 16)),
    bf2f((unsigned short)(wr.z & 0xffff)), bf2f((unsigned short)(wr.z >> 16)),
    bf2f((unsigned short)(wr.w & 0xffff)), bf2f((unsigned short)(wr.w >> 16))};
  unsigned short o[8];
#pragma unroll
  for (int v = 0; v < 8; ++v)
    o[v] = f2bf(fmaxf(acc[v] * inv + rt[v] + b2[f0 + v], 0.f));
  uint4 pk;
  pk.x = (unsigned)o[0] | ((unsigned)o[1] << 16);
  pk.y = (unsigned)o[2] | ((unsigned)o[3] << 16);
  pk.z = (unsigned)o[4] | ((unsigned)o[5] << 16);
  pk.w = (unsigned)o[6] | ((unsigned)o[7] << 16);
  *reinterpret_cast<uint4*>(h2 + (size_t)node * 512 + f0) = pk;
}

__global__ void head_agg_kernel(const float* __restrict__ P3,
                                const int* __restrict__ rs, const int* __restrict__ cs,
                                const float* __restrict__ invdeg,
                                const float* __restrict__ bmu, const float* __restrict__ bls,
                                float* __restrict__ outmu, float* __restrict__ outls, int M) {
  int idx = blockIdx.x * blockDim.x + threadIdx.x;
  int node = idx >> 4;
  int c = idx & 15;
  if (node >= M) return;
  int relc = (c < 8) ? c : (16 + (c - 8));
  float acc = 0.f;
  int e1 = rs[node + 1];
  for (int e = rs[node]; e < e1; ++e) acc += P3[(size_t)cs[e] * 128 + relc];
  float v = acc * invdeg[node] + P3[(size_t)node * 128 + relc + 8]
          + ((c < 8) ? bmu[c] : bls[c - 8]);
  if (c < 8) outmu[(size_t)node * 8 + c] = v;
  else outls[(size_t)node * 8 + (c - 8)] = v;
}

// ---------------- weight transposes (LDS-tiled, coalesced) ----------------

__device__ __forceinline__ void ttile(const float* __restrict__ src, int Nw,
                                      unsigned short* __restrict__ dst, int ldd,
                                      int rowoff, int coloff,
                                      int tileIdx, int tilesN, float (*tile)[33]) {
  int tk = tileIdx / tilesN, tn = tileIdx % tilesN;
  int k0 = tk * 32, n0 = tn * 32;
  int tx = threadIdx.x & 31, ty = threadIdx.x >> 5;
#pragma unroll
  for (int s = 0; s < 4; ++s)
    tile[ty + s * 8][tx] = src[(size_t)(k0 + ty + s * 8) * Nw + n0 + tx];
  __syncthreads();
#pragma unroll
  for (int s = 0; s < 4; ++s)
    dst[(size_t)(rowoff + n0 + ty + s * 8) * ldd + coloff + k0 + tx] =
        f2bf(tile[tx][ty + s * 8]);
}

__global__ void wtrans_all_kernel(const float* __restrict__ w1_rel, const float* __restrict__ w1_root,
                                  const float* __restrict__ w2_rel, const float* __restrict__ w2_root,
                                  const float* __restrict__ wmu_rel, const float* __restrict__ wmu_root,
                                  const float* __restrict__ wls_rel, const float* __restrict__ wls_root,
                                  unsigned short* __restrict__ Bt1,
                                  unsigned short* __restrict__ Bt2,
                                  unsigned short* __restrict__ Bt3) {
  __shared__ float tile[32][33];
  int b = blockIdx.x;
  if (b < 128)       ttile(w1_rel, 1024, Bt1, 256, 0, 0, b, 32, tile);
  else if (b < 256)  ttile(w1_root, 1024, Bt1, 256, 0, 128, b - 128, 32, tile);
  else if (b < 768)  ttile(w2_rel, 512, Bt2, 1024, 0, 0, b - 256, 16, tile);
  else if (b < 1280) ttile(w2_root, 512, Bt2, 1024, 512, 0, b - 768, 16, tile);
  else {
    int idx = (b - 1280) * 256 + threadIdx.x;
    int n = idx >> 9, k = idx & 511;
    float v;
    if (n < 8) v = wmu_rel[(size_t)k * 8 + n];
    else if (n < 16) v = wmu_root[(size_t)k * 8 + (n - 8)];
    else if (n < 24) v = wls_rel[(size_t)k * 8 + (n - 16)];
    else v = wls_root[(size_t)k * 8 + (n - 24)];
    Bt3[(size_t)n * 512 + k] = f2bf(v);
  }
}

// ------ 128x128 GEMM, 4 waves, ring-2, single barrier/step, swizzled ------
// C[M][N] = A[M][K] * Bt[N][K]^T (+bias)(relu). BK=32.
// LDS 32 KB (2 buf x (A 8KB + B 8KB)) -> 4 blocks/CU (16 waves/CU) at
// launch_bounds(256,4). Schedule: stage(t+1) issued BEFORE compute(t);
// one vmcnt(0)+lgkmcnt(0)+barrier per K-step (catalog minimum-2-phase).
// Both-sides slot-XOR swizzle: global source pre-swizzled, reads swizzled.
// Caller: Mpad128 rows readable, N%128==0, K%32==0, K>=64.
__launch_bounds__(256, 4)
__global__ void gemm_db_kernel(const unsigned short* __restrict__ A, int lda,
                               const unsigned short* __restrict__ Bt, int ldb,
                               const float* __restrict__ bias,
                               void* __restrict__ outp, int ldo,
                               int M, int N, int K, int relu, int out_f32, int gx) {
  __shared__ unsigned short As[2 * 4096];
  __shared__ unsigned short Bs[2 * 4096];
  const int tid = threadIdx.x;
  const int lane = tid & 63;
  const int w = tid >> 6;
  const int wr = w >> 1, wc = w & 1;
  const int lr = lane & 15, lk = lane >> 4;
  const int sw8 = (lk ^ ((lr >> 1) & 3)) * 8;  // swizzled read slot (shorts)

  // bijective XCD swizzle (m204)
  int nwg = gridDim.x, orig = blockIdx.x;
  int q = nwg >> 3, r = nwg & 7;
  int xcd = orig & 7, lid = orig >> 3;
  int swz = (xcd < r ? xcd * (q + 1) : r * (q + 1) + (xcd - r) * q) + lid;
  int m0 = (swz / gx) * 128, n0 = (swz % gx) * 128;

  f32x4 acc[4][4];
#pragma unroll
  for (int i = 0; i < 4; ++i)
#pragma unroll
    for (int j = 0; j < 4; ++j) acc[i][j] = (f32x4)0.0f;

  // staging: row r0 = tid>>2 (0..63, plus +64 row), phys slot = tid&3,
  // global slot slog = (tid&3) ^ ((r0>>1)&3)  (row+64 shares xor term)
  const int r0 = tid >> 2;
  const int slog = ((tid & 3) ^ ((r0 >> 1) & 3)) * 8;
  const unsigned short* gA = A + (size_t)(m0 + r0) * lda + slog;
  const unsigned short* gB = Bt + (size_t)(n0 + r0) * ldb + slog;
  const size_t a64 = (size_t)64 * lda, b64 = (size_t)64 * ldb;
  unsigned short* wa = As + w * 512;
  unsigned short* wb = Bs + w * 512;

  auto STG = [&](int s, int t) {
    const unsigned short* a = gA + (size_t)t * 32;
    const unsigned short* b = gB + (size_t)t * 32;
    gl_lds16(a, wa + s * 4096);
    gl_lds16(a + a64, wa + s * 4096 + 2048);
    gl_lds16(b, wb + s * 4096);
    gl_lds16(b + b64, wb + s * 4096 + 2048);
  };

  const int nt = K >> 5;
  STG(0, 0);
  asm volatile("s_waitcnt vmcnt(0)" ::: "memory");
  __builtin_amdgcn_s_barrier();

  int buf = 0;
  for (int t = 0; t < nt; ++t) {
    if (t + 1 < nt) STG(buf ^ 1, t + 1);
    const unsigned short* as_ = As + buf * 4096;
    const unsigned short* bs_ = Bs + buf * 4096;
    short8 af[4], bf[4];
#pragma unroll
    for (int i = 0; i < 4; ++i) {
      af[i] = *reinterpret_cast<const short8*>(&as_[(wr * 64 + i * 16 + lr) * 32 + sw8]);
      bf[i] = *reinterpret_cast<const short8*>(&bs_[(wc * 64 + i * 16 + lr) * 32 + sw8]);
    }
    __builtin_amdgcn_s_setprio(1);
#pragma unroll
    for (int i = 0; i < 4; ++i)
#pragma unroll
      for (int j = 0; j < 4; ++j)
        acc[i][j] = __builtin_amdgcn_mfma_f32_16x16x32_bf16(af[i], bf[j], acc[i][j], 0, 0, 0);
    __builtin_amdgcn_s_setprio(0);
    if (t + 1 < nt) {
      // next buffer fully staged; this buffer's reads done -> safe to re-stage
      asm volatile("s_waitcnt vmcnt(0) lgkmcnt(0)" ::: "memory");
      __builtin_amdgcn_s_barrier();
    }
    buf ^= 1;
  }

#pragma unroll
  for (int i = 0; i < 4; ++i) {
    int row_b = m0 + wr * 64 + i * 16 + lk * 4;
#pragma unroll
    for (int j = 0; j < 4; ++j) {
      int col = n0 + wc * 64 + j * 16 + lr;
      float bv = bias ? bias[col] : 0.f;
#pragma unroll
      for (int rr = 0; rr < 4; ++rr) {
        int row = row_b + rr;
        if (row < M) {
          float v = acc[i][j][rr] + bv;
          if (relu) v = fmaxf(v, 0.f);
          if (out_f32) ((float*)outp)[(size_t)row * ldo + col] = v;
          else ((unsigned short*)outp)[(size_t)row * ldo + col] = f2bf(v);
        }
      }
    }
  }
}

// ---------------- host ----------------

extern "C" void kernel_launch(void* const* d_in, const int* in_sizes, int n_in,
                              void* d_out, int out_size, void* d_ws, size_t ws_size,
                              hipStream_t stream) {
  const float* x = (const float*)d_in[0];
  const void* edge = d_in[1];
  const float* w1_rel = (const float*)d_in[2];
  const float* b1 = (const float*)d_in[3];
  const float* w1_root = (const float*)d_in[4];
  const float* w2_rel = (const float*)d_in[5];
  const float* b2 = (const float*)d_in[6];
  const float* w2_root = (const float*)d_in[7];
  const float* wmu_rel = (const float*)d_in[8];
  const float* bmu = (const float*)d_in[9];
  const float* wmu_root = (const float*)d_in[10];
  const float* wls_rel = (const float*)d_in[11];
  const float* bls = (const float*)d_in[12];
  const float* wls_root = (const float*)d_in[13];

  const int FIN = 128, H1 = 1024, H2 = 512;
  const int M = in_sizes[0] / FIN;   // 20000
  const int E = in_sizes[1] / 2;     // 160000
  const int Mpad = ((M + 127) / 128) * 128;   // 20096
  const int gy = Mpad / 128;                  // 157

  char* ws = (char*)d_ws;
  size_t off = 0;
  auto alloc = [&](size_t bytes) -> char* {
    char* p = ws + off;
    off = (off + bytes + 255) & ~(size_t)255;
    return p;
  };
  int* flag = (int*)alloc(4);
  int* deg = (int*)alloc((size_t)M * 4);
  int* cursor = (int*)alloc((size_t)M * 4);
  int* rs = (int*)alloc((size_t)(M + 1) * 4);
  float* invdeg = (float*)alloc((size_t)M * 4);
  int* cs = (int*)alloc((size_t)E * 4);
  unsigned short* A1 = (unsigned short*)alloc((size_t)Mpad * 256 * 2);   // [mean(x)|x]
  unsigned short* h1 = (unsigned short*)alloc((size_t)Mpad * 1024 * 2);
  unsigned short* P2 = (unsigned short*)alloc((size_t)Mpad * 1024 * 2);  // [h1@w2_rel | h1@w2_root]
  unsigned short* h2 = (unsigned short*)alloc((size_t)Mpad * 512 * 2);
  float* P3 = (float*)alloc((size_t)Mpad * 128 * 4);                     // heads pre-agg
  unsigned short* Bt1 = (unsigned short*)alloc((size_t)H1 * 256 * 2);
  unsigned short* Bt2 = (unsigned short*)alloc((size_t)1024 * 1024 * 2);
  unsigned short* Bt3 = (unsigned short*)alloc((size_t)128 * 512 * 2);

  // CSR build
  init_kernel<<<64, 256, 0, stream>>>(deg, M, cursor, M, flag, (const long long*)edge, 2048, M);
  count_kernel<<<256, 256, 0, stream>>>(edge, E, flag, deg);
  scan_kernel<<<1, 1024, 0, stream>>>(deg, rs, invdeg, M);
  fill_kernel<<<256, 256, 0, stream>>>(edge, E, flag, rs, cursor, cs);

  // Weights (coalesced tiled transpose, one launch)
  wtrans_all_kernel<<<1344, 256, 0, stream>>>(w1_rel, w1_root, w2_rel, w2_root,
                                              wmu_rel, wmu_root, wls_rel, wls_root,
                                              Bt1, Bt2, Bt3);

  // Layer 1: A1 = [mean(x) | x] bf16; h1 = relu(A1 @ Bt1^T + b1)
  agg1_kernel<<<M, 128, 0, stream>>>(x, rs, cs, invdeg, A1);
  gemm_db_kernel<<<(H1 / 128) * gy, 256, 0, stream>>>(
      A1, 256, Bt1, 256, b1, h1, 1024, M, H1, 256, 1, 0, H1 / 128);

  // Layer 2 (commuted): P2 = h1 @ [w2_rel | w2_root]; h2 = relu(mean_agg(P2_rel) + P2_root + b2)
  gemm_db_kernel<<<(1024 / 128) * gy, 256, 0, stream>>>(
      h1, 1024, Bt2, 1024, nullptr, P2, 1024, M, 1024, 1024, 0, 0, 1024 / 128);
  agg2_kernel<<<(M + 1) / 2, 128, 0, stream>>>(P2, rs, cs, invdeg, b2, h2, M);

  // Heads (commuted): P3 = h2 @ [4 head mats]^T (fp32 out); out = mean_agg(P3_rel) + P3_root + bias
  gemm_db_kernel<<<1 * gy, 256, 0, stream>>>(
      h2, 512, Bt3, 512, nullptr, P3, 128, M, 128, 512, 0, 1, 1);
  float* outmu = (float*)d_out;
  float* outls = outmu + (size_t)M * 8;
  head_agg_kernel<<<(M * 16 + 255) / 256, 256, 0, stream>>>(
      P3, rs, cs, invdeg, bmu, bls, outmu, outls, M);
}

// Round 10
// 269.634 us; speedup vs baseline: 1.2001x; 1.0431x over previous
//
#include <hip/hip_runtime.h>

typedef __attribute__((ext_vector_type(8))) short short8;
typedef __attribute__((ext_vector_type(4))) float f32x4;
typedef unsigned long long u64;

__device__ __forceinline__ unsigned short f2bf(float f) {
  union { float f; unsigned u; } v; v.f = f;
  unsigned u = v.u;
  unsigned r = (u + 0x7FFFu + ((u >> 16) & 1u)) >> 16;  // RTNE
  return (unsigned short)r;
}
__device__ __forceinline__ float bf2f(unsigned short s) {
  union { unsigned u; float f; } v; v.u = ((unsigned)s) << 16;
  return v.f;
}

// async global->LDS, 16B per lane; LDS dest = wave-uniform base + lane*16
__device__ __forceinline__ void gl_lds16(const unsigned short* g, unsigned short* l) {
  __builtin_amdgcn_global_load_lds(
      (const __attribute__((address_space(1))) void*)g,
      (__attribute__((address_space(3))) void*)l, 16, 0, 0);
}

// ---------------- prep: zero deg/cursor + flag + weight transposes ----------------

__device__ __forceinline__ void ttile(const float* __restrict__ src, int Nw,
                                      unsigned short* __restrict__ dst, int ldd,
                                      int rowoff, int coloff,
                                      int tileIdx, int tilesN, float (*tile)[33]) {
  int tk = tileIdx / tilesN, tn = tileIdx % tilesN;
  int k0 = tk * 32, n0 = tn * 32;
  int tx = threadIdx.x & 31, ty = threadIdx.x >> 5;
#pragma unroll
  for (int s = 0; s < 4; ++s)
    tile[ty + s * 8][tx] = src[(size_t)(k0 + ty + s * 8) * Nw + n0 + tx];
  __syncthreads();
#pragma unroll
  for (int s = 0; s < 4; ++s)
    dst[(size_t)(rowoff + n0 + ty + s * 8) * ldd + coloff + k0 + tx] =
        f2bf(tile[tx][ty + s * 8]);
}

__global__ void prep_kernel(int* deg, int* cursor, int n, int* flag,
                            const float* __restrict__ w1_rel, const float* __restrict__ w1_root,
                            const float* __restrict__ w2_rel, const float* __restrict__ w2_root,
                            const float* __restrict__ wmu_rel, const float* __restrict__ wmu_root,
                            const float* __restrict__ wls_rel, const float* __restrict__ wls_root,
                            unsigned short* __restrict__ Bt1,
                            unsigned short* __restrict__ Bt2,
                            unsigned short* __restrict__ Bt3) {
  __shared__ float tile[32][33];
  int b = blockIdx.x;
  if (b >= 1344) {  // 64 init blocks
    int i = (b - 1344) * blockDim.x + threadIdx.x;
    int stride = 64 * blockDim.x;
    for (int j = i; j < n; j += stride) { deg[j] = 0; cursor[j] = 0; }
    if (i == 0) *flag = 1;
    return;
  }
  if (b < 128)       ttile(w1_rel, 1024, Bt1, 256, 0, 0, b, 32, tile);
  else if (b < 256)  ttile(w1_root, 1024, Bt1, 256, 0, 128, b - 128, 32, tile);
  else if (b < 768)  ttile(w2_rel, 512, Bt2, 1024, 0, 0, b - 256, 16, tile);
  else if (b < 1280) ttile(w2_root, 512, Bt2, 1024, 512, 0, b - 768, 16, tile);
  else {
    int idx = (b - 1280) * 256 + threadIdx.x;  // 64 blocks * 256 = 16384 = 32*512
    int nn = idx >> 9, k = idx & 511;
    float v;
    if (nn < 8) v = wmu_rel[(size_t)k * 8 + nn];
    else if (nn < 16) v = wmu_root[(size_t)k * 8 + (nn - 8)];
    else if (nn < 24) v = wls_rel[(size_t)k * 8 + (nn - 16)];
    else v = wls_root[(size_t)k * 8 + (nn - 24)];
    Bt3[(size_t)nn * 512 + k] = f2bf(v);
  }
}

// Detect whether edge buffer is int64 (values all in [0,n)) or int32.
__global__ void detect_kernel(const long long* p, int nslots, int n_nodes, int* flag) {
  int i = blockIdx.x * blockDim.x + threadIdx.x;
  if (i < nslots) {
    long long v = p[i];
    if (v < 0 || v >= n_nodes) atomicAnd(flag, 0);
  }
}

__device__ __forceinline__ int edge_at(const void* p, int is64, size_t idx) {
  return is64 ? (int)((const long long*)p)[idx] : ((const int*)p)[idx];
}

__global__ void count_kernel(const void* edges, int E, const int* flag, int* deg) {
  int is64 = *flag;
  int i = blockIdx.x * blockDim.x + threadIdx.x;
  int stride = gridDim.x * blockDim.x;
  for (int e = i; e < E; e += stride) {
    int d = edge_at(edges, is64, (size_t)E + e);
    atomicAdd(&deg[d], 1);
  }
}

__global__ void scan_kernel(const int* __restrict__ deg, int* __restrict__ rs,
                            float* __restrict__ invdeg, int n) {
  __shared__ int ssum[1024];
  int tid = threadIdx.x;
  int chunk = (n + 1023) >> 10;
  int start = tid * chunk;
  int end = min(start + chunk, n);
  int s = 0;
  for (int i = start; i < end; ++i) s += deg[i];
  ssum[tid] = s;
  __syncthreads();
  for (int off = 1; off < 1024; off <<= 1) {
    int t = (tid >= off) ? ssum[tid - off] : 0;
    __syncthreads();
    ssum[tid] += t;
    __syncthreads();
  }
  int run = (tid ? ssum[tid - 1] : 0);
  if (tid == 0) rs[0] = 0;
  for (int i = start; i < end; ++i) {
    int d = deg[i];
    run += d;
    rs[i + 1] = run;
    invdeg[i] = 1.0f / fmaxf((float)d, 1.0f);
  }
}

__global__ void fill_kernel(const void* edges, int E, const int* flag,
                            const int* __restrict__ rs, int* cursor, int* col_src) {
  int is64 = *flag;
  int i = blockIdx.x * blockDim.x + threadIdx.x;
  int stride = gridDim.x * blockDim.x;
  for (int e = i; e < E; e += stride) {
    int d = edge_at(edges, is64, (size_t)E + e);
    int s = edge_at(edges, is64, (size_t)e);
    int p = atomicAdd(&cursor[d], 1);
    col_src[rs[d] + p] = s;
  }
}

// ---------------- aggregation ----------------

__global__ void agg1_kernel(const float* __restrict__ x,
                            const int* __restrict__ rs, const int* __restrict__ cs,
                            const float* __restrict__ invdeg,
                            unsigned short* __restrict__ A1) {
  int node = blockIdx.x;
  int f = threadIdx.x;  // 128
  float xi = x[(size_t)node * 128 + f];
  float acc = 0.f;
  int e1 = rs[node + 1];
  for (int e = rs[node]; e < e1; ++e) {
    acc += x[(size_t)cs[e] * 128 + f];
  }
  A1[(size_t)node * 256 + f] = f2bf(acc * invdeg[node]);
  A1[(size_t)node * 256 + 128 + f] = f2bf(xi);
}

// layer-2 combine, 2 nodes/block, 16B per lane:
// h2[i][c] = relu( inv*sum_j P2[j][c] + P2[i][512+c] + b2[c] )
__global__ void agg2_kernel(const unsigned short* __restrict__ P2,
                            const int* __restrict__ rs, const int* __restrict__ cs,
                            const float* __restrict__ invdeg,
                            const float* __restrict__ b2,
                            unsigned short* __restrict__ h2, int M) {
  int node = blockIdx.x * 2 + (threadIdx.x >> 6);
  if (node >= M) return;
  int f0 = (threadIdx.x & 63) * 8;  // 64 lanes x 8 cols = 512
  float acc[8];
#pragma unroll
  for (int v = 0; v < 8; ++v) acc[v] = 0.f;
  int e1 = rs[node + 1];
  for (int e = rs[node]; e < e1; ++e) {
    int s = cs[e];
    uint4 w = *reinterpret_cast<const uint4*>(P2 + (size_t)s * 1024 + f0);
    acc[0] += bf2f((unsigned short)(w.x & 0xffff));
    acc[1] += bf2f((unsigned short)(w.x >> 16));
    acc[2] += bf2f((unsigned short)(w.y & 0xffff));
    acc[3] += bf2f((unsigned short)(w.y >> 16));
    acc[4] += bf2f((unsigned short)(w.z & 0xffff));
    acc[5] += bf2f((unsigned short)(w.z >> 16));
    acc[6] += bf2f((unsigned short)(w.w & 0xffff));
    acc[7] += bf2f((unsigned short)(w.w >> 16));
  }
  float inv = invdeg[node];
  uint4 wr = *reinterpret_cast<const uint4*>(P2 + (size_t)node * 1024 + 512 + f0);
  float rt[8] = {
    bf2f((unsigned short)(wr.x & 0xffff)), bf2f((unsigned short)(wr.x >> 16)),
    bf2f((unsigned short)(wr.y & 0xffff)), bf2f((unsigned short)(wr.y >> 16)),
    bf2f((unsigned short)(wr.z & 0xffff)), bf2f((unsigned short)(wr.z >> 16)),
    bf2f((unsigned short)(wr.w & 0xffff)), bf2f((unsigned short)(wr.w >> 16))};
  unsigned short o[8];
#pragma unroll
  for (int v = 0; v < 8; ++v)
    o[v] = f2bf(fmaxf(acc[v] * inv + rt[v] + b2[f0 + v], 0.f));
  uint4 pk;
  pk.x = (unsigned)o[0] | ((unsigned)o[1] << 16);
  pk.y = (unsigned)o[2] | ((unsigned)o[3] << 16);
  pk.z = (unsigned)o[4] | ((unsigned)o[5] << 16);
  pk.w = (unsigned)o[6] | ((unsigned)o[7] << 16);
  *reinterpret_cast<uint4*>(h2 + (size_t)node * 512 + f0) = pk;
}

// heads combine: P3 [Mpad][32] f32: cols 0-7 mu_rel, 8-15 mu_root, 16-23 ls_rel, 24-31 ls_root
__global__ void head_agg_kernel(const float* __restrict__ P3,
                                const int* __restrict__ rs, const int* __restrict__ cs,
                                const float* __restrict__ invdeg,
                                const float* __restrict__ bmu, const float* __restrict__ bls,
                                float* __restrict__ outmu, float* __restrict__ outls, int M) {
  int idx = blockIdx.x * blockDim.x + threadIdx.x;
  int node = idx >> 4;
  int c = idx & 15;
  if (node >= M) return;
  int relc = (c < 8) ? c : (16 + (c - 8));
  float acc = 0.f;
  int e1 = rs[node + 1];
  for (int e = rs[node]; e < e1; ++e) acc += P3[(size_t)cs[e] * 32 + relc];
  float v = acc * invdeg[node] + P3[(size_t)node * 32 + relc + 8]
          + ((c < 8) ? bmu[c] : bls[c - 8]);
  if (c < 8) outmu[(size_t)node * 8 + c] = v;
  else outls[(size_t)node * 8 + (c - 8)] = v;
}

// ------ 128x128 GEMM, 4 waves, ring-2, single barrier/step, swizzled ------
// (R9 kernel, frozen at plateau.)
__launch_bounds__(256, 4)
__global__ void gemm_db_kernel(const unsigned short* __restrict__ A, int lda,
                               const unsigned short* __restrict__ Bt, int ldb,
                               const float* __restrict__ bias,
                               void* __restrict__ outp, int ldo,
                               int M, int N, int K, int relu, int out_f32, int gx) {
  __shared__ unsigned short As[2 * 4096];
  __shared__ unsigned short Bs[2 * 4096];
  const int tid = threadIdx.x;
  const int lane = tid & 63;
  const int w = tid >> 6;
  const int wr = w >> 1, wc = w & 1;
  const int lr = lane & 15, lk = lane >> 4;
  const int sw8 = (lk ^ ((lr >> 1) & 3)) * 8;

  int nwg = gridDim.x, orig = blockIdx.x;
  int q = nwg >> 3, r = nwg & 7;
  int xcd = orig & 7, lid = orig >> 3;
  int swz = (xcd < r ? xcd * (q + 1) : r * (q + 1) + (xcd - r) * q) + lid;
  int m0 = (swz / gx) * 128, n0 = (swz % gx) * 128;

  f32x4 acc[4][4];
#pragma unroll
  for (int i = 0; i < 4; ++i)
#pragma unroll
    for (int j = 0; j < 4; ++j) acc[i][j] = (f32x4)0.0f;

  const int r0 = tid >> 2;
  const int slog = ((tid & 3) ^ ((r0 >> 1) & 3)) * 8;
  const unsigned short* gA = A + (size_t)(m0 + r0) * lda + slog;
  const unsigned short* gB = Bt + (size_t)(n0 + r0) * ldb + slog;
  const size_t a64 = (size_t)64 * lda, b64 = (size_t)64 * ldb;
  unsigned short* wa = As + w * 512;
  unsigned short* wb = Bs + w * 512;

  auto STG = [&](int s, int t) {
    const unsigned short* a = gA + (size_t)t * 32;
    const unsigned short* b = gB + (size_t)t * 32;
    gl_lds16(a, wa + s * 4096);
    gl_lds16(a + a64, wa + s * 4096 + 2048);
    gl_lds16(b, wb + s * 4096);
    gl_lds16(b + b64, wb + s * 4096 + 2048);
  };

  const int nt = K >> 5;
  STG(0, 0);
  asm volatile("s_waitcnt vmcnt(0)" ::: "memory");
  __builtin_amdgcn_s_barrier();

  int buf = 0;
  for (int t = 0; t < nt; ++t) {
    if (t + 1 < nt) STG(buf ^ 1, t + 1);
    const unsigned short* as_ = As + buf * 4096;
    const unsigned short* bs_ = Bs + buf * 4096;
    short8 af[4], bf[4];
#pragma unroll
    for (int i = 0; i < 4; ++i) {
      af[i] = *reinterpret_cast<const short8*>(&as_[(wr * 64 + i * 16 + lr) * 32 + sw8]);
      bf[i] = *reinterpret_cast<const short8*>(&bs_[(wc * 64 + i * 16 + lr) * 32 + sw8]);
    }
    __builtin_amdgcn_s_setprio(1);
#pragma unroll
    for (int i = 0; i < 4; ++i)
#pragma unroll
      for (int j = 0; j < 4; ++j)
        acc[i][j] = __builtin_amdgcn_mfma_f32_16x16x32_bf16(af[i], bf[j], acc[i][j], 0, 0, 0);
    __builtin_amdgcn_s_setprio(0);
    if (t + 1 < nt) {
      asm volatile("s_waitcnt vmcnt(0) lgkmcnt(0)" ::: "memory");
      __builtin_amdgcn_s_barrier();
    }
    buf ^= 1;
  }

#pragma unroll
  for (int i = 0; i < 4; ++i) {
    int row_b = m0 + wr * 64 + i * 16 + lk * 4;
#pragma unroll
    for (int j = 0; j < 4; ++j) {
      int col = n0 + wc * 64 + j * 16 + lr;
      float bv = bias ? bias[col] : 0.f;
#pragma unroll
      for (int rr = 0; rr < 4; ++rr) {
        int row = row_b + rr;
        if (row < M) {
          float v = acc[i][j][rr] + bv;
          if (relu) v = fmaxf(v, 0.f);
          if (out_f32) ((float*)outp)[(size_t)row * ldo + col] = v;
          else ((unsigned short*)outp)[(size_t)row * ldo + col] = f2bf(v);
        }
      }
    }
  }
}

// ------ heads GEMM: C[M][32] = h2[M][512] @ Bt3[32][512]^T, fp32 out ------
// Block: 128 rows, 4 waves (wave w -> rows w*32..w*32+31), acc[2][2].
// B staged ONCE to LDS in per-k-tile [32][32-short] sublayout (same swizzle
// family as gemm_db -> conflict-free reads); A streamed via ring-2 gl_lds.
__launch_bounds__(256, 3)
__global__ void gemm_heads_kernel(const unsigned short* __restrict__ A,
                                  const unsigned short* __restrict__ Bt3,
                                  float* __restrict__ P3, int M, int gx_unused) {
  __shared__ unsigned short Bs[16 * 1024];  // 16 k-tiles x [32 rows][32 shorts] = 32 KB
  __shared__ unsigned short As[2 * 4096];   // ring-2 x [128][32]
  const int tid = threadIdx.x;
  const int lane = tid & 63;
  const int w = tid >> 6;
  const int lr = lane & 15, lk = lane >> 4;
  const int sw8 = (lk ^ ((lr >> 1) & 3)) * 8;

  int nwg = gridDim.x, orig = blockIdx.x;
  int q = nwg >> 3, r = nwg & 7;
  int xcd = orig & 7, lid = orig >> 3;
  int swz = (xcd < r ? xcd * (q + 1) : r * (q + 1) + (xcd - r) * q) + lid;
  int m0 = swz * 128;

  // stage all of B once: 2048 uint4; j -> row n = j>>6, global slot p = j&63;
  // phys in-group slot = (p&3) ^ ((n>>1)&3); LDS short-off = (p>>2)*1024 + n*32 + phys*8
  for (int i = 0; i < 8; ++i) {
    int j = i * 256 + tid;
    int n = j >> 6, p = j & 63;
    int x = (n >> 1) & 3;
    uint4 v = *reinterpret_cast<const uint4*>(Bt3 + (size_t)n * 512 + ((p & ~3) | ((p & 3) ^ x)) * 8);
    *reinterpret_cast<uint4*>(&Bs[(p >> 2) * 1024 + n * 32 + (p & 3) * 8]) = v;
  }

  f32x4 acc[2][2];
#pragma unroll
  for (int i = 0; i < 2; ++i)
#pragma unroll
    for (int j = 0; j < 2; ++j) acc[i][j] = (f32x4)0.0f;

  const int r0 = tid >> 2;
  const int slog = ((tid & 3) ^ ((r0 >> 1) & 3)) * 8;
  const unsigned short* gA = A + (size_t)(m0 + r0) * 512 + slog;
  const size_t a64 = (size_t)64 * 512;
  unsigned short* wa = As + w * 512;

  auto STG = [&](int s, int t) {
    const unsigned short* a = gA + (size_t)t * 32;
    gl_lds16(a, wa + s * 4096);
    gl_lds16(a + a64, wa + s * 4096 + 2048);
  };

  STG(0, 0);
  __syncthreads();  // drains vm+lgkm: B staged, A tile 0 landed

  int buf = 0;
  const int nt = 16;
  for (int t = 0; t < nt; ++t) {
    if (t + 1 < nt) STG(buf ^ 1, t + 1);
    const unsigned short* as_ = As + buf * 4096;
    short8 af[2], bf[2];
#pragma unroll
    for (int i = 0; i < 2; ++i) {
      af[i] = *reinterpret_cast<const short8*>(&as_[(w * 32 + i * 16 + lr) * 32 + sw8]);
      bf[i] = *reinterpret_cast<const short8*>(&Bs[t * 1024 + (i * 16 + lr) * 32 + sw8]);
    }
#pragma unroll
    for (int i = 0; i < 2; ++i)
#pragma unroll
      for (int j = 0; j < 2; ++j)
        acc[i][j] = __builtin_amdgcn_mfma_f32_16x16x32_bf16(af[i], bf[j], acc[i][j], 0, 0, 0);
    if (t + 1 < nt) {
      asm volatile("s_waitcnt vmcnt(0) lgkmcnt(0)" ::: "memory");
      __builtin_amdgcn_s_barrier();
    }
    buf ^= 1;
  }

#pragma unroll
  for (int i = 0; i < 2; ++i) {
    int row_b = m0 + w * 32 + i * 16 + lk * 4;
#pragma unroll
    for (int j = 0; j < 2; ++j) {
      int col = j * 16 + lr;
#pragma unroll
      for (int rr = 0; rr < 4; ++rr) {
        int row = row_b + rr;
        if (row < M) P3[(size_t)row * 32 + col] = acc[i][j][rr];
      }
    }
  }
}

// ---------------- host ----------------

extern "C" void kernel_launch(void* const* d_in, const int* in_sizes, int n_in,
                              void* d_out, int out_size, void* d_ws, size_t ws_size,
                              hipStream_t stream) {
  const float* x = (const float*)d_in[0];
  const void* edge = d_in[1];
  const float* w1_rel = (const float*)d_in[2];
  const float* b1 = (const float*)d_in[3];
  const float* w1_root = (const float*)d_in[4];
  const float* w2_rel = (const float*)d_in[5];
  const float* b2 = (const float*)d_in[6];
  const float* w2_root = (const float*)d_in[7];
  const float* wmu_rel = (const float*)d_in[8];
  const float* bmu = (const float*)d_in[9];
  const float* wmu_root = (const float*)d_in[10];
  const float* wls_rel = (const float*)d_in[11];
  const float* bls = (const float*)d_in[12];
  const float* wls_root = (const float*)d_in[13];

  const int FIN = 128, H1 = 1024, H2 = 512;
  const int M = in_sizes[0] / FIN;   // 20000
  const int E = in_sizes[1] / 2;     // 160000
  const int Mpad = ((M + 127) / 128) * 128;   // 20096
  const int gy = Mpad / 128;                  // 157

  char* ws = (char*)d_ws;
  size_t off = 0;
  auto alloc = [&](size_t bytes) -> char* {
    char* p = ws + off;
    off = (off + bytes + 255) & ~(size_t)255;
    return p;
  };
  int* flag = (int*)alloc(4);
  int* deg = (int*)alloc((size_t)M * 4);
  int* cursor = (int*)alloc((size_t)M * 4);
  int* rs = (int*)alloc((size_t)(M + 1) * 4);
  float* invdeg = (float*)alloc((size_t)M * 4);
  int* cs = (int*)alloc((size_t)E * 4);
  unsigned short* A1 = (unsigned short*)alloc((size_t)Mpad * 256 * 2);   // [mean(x)|x]
  unsigned short* h1 = (unsigned short*)alloc((size_t)Mpad * 1024 * 2);
  unsigned short* P2 = (unsigned short*)alloc((size_t)Mpad * 1024 * 2);  // [h1@w2_rel | h1@w2_root]
  unsigned short* h2 = (unsigned short*)alloc((size_t)Mpad * 512 * 2);
  float* P3 = (float*)alloc((size_t)Mpad * 32 * 4);                      // heads pre-agg
  unsigned short* Bt1 = (unsigned short*)alloc((size_t)H1 * 256 * 2);
  unsigned short* Bt2 = (unsigned short*)alloc((size_t)1024 * 1024 * 2);
  unsigned short* Bt3 = (unsigned short*)alloc((size_t)32 * 512 * 2);

  // prep: zero deg/cursor + flag + all weight transposes (one launch)
  prep_kernel<<<1408, 256, 0, stream>>>(deg, cursor, M, flag,
                                        w1_rel, w1_root, w2_rel, w2_root,
                                        wmu_rel, wmu_root, wls_rel, wls_root,
                                        Bt1, Bt2, Bt3);
  detect_kernel<<<8, 256, 0, stream>>>((const long long*)edge, 2048, M, flag);
  count_kernel<<<256, 256, 0, stream>>>(edge, E, flag, deg);
  scan_kernel<<<1, 1024, 0, stream>>>(deg, rs, invdeg, M);
  fill_kernel<<<256, 256, 0, stream>>>(edge, E, flag, rs, cursor, cs);

  // Layer 1: A1 = [mean(x) | x] bf16; h1 = relu(A1 @ Bt1^T + b1)
  agg1_kernel<<<M, 128, 0, stream>>>(x, rs, cs, invdeg, A1);
  gemm_db_kernel<<<(H1 / 128) * gy, 256, 0, stream>>>(
      A1, 256, Bt1, 256, b1, h1, 1024, M, H1, 256, 1, 0, H1 / 128);

  // Layer 2 (commuted): P2 = h1 @ [w2_rel | w2_root]; h2 = relu(mean_agg(P2_rel) + P2_root + b2)
  gemm_db_kernel<<<(1024 / 128) * gy, 256, 0, stream>>>(
      h1, 1024, Bt2, 1024, nullptr, P2, 1024, M, 1024, 1024, 0, 0, 1024 / 128);
  agg2_kernel<<<(M + 1) / 2, 128, 0, stream>>>(P2, rs, cs, invdeg, b2, h2, M);

  // Heads (commuted): P3 = h2 @ [4 head mats]^T (fp32, 32 cols);
  // out = mean_agg(P3_rel) + P3_root + bias
  gemm_heads_kernel<<<gy, 256, 0, stream>>>(h2, Bt3, P3, M, 1);
  float* outmu = (float*)d_out;
  float* outls = outmu + (size_t)M * 8;
  head_agg_kernel<<<(M * 16 + 255) / 256, 256, 0, stream>>>(
      P3, rs, cs, invdeg, bmu, bls, outmu, outls, M);
}